// Round 23
// baseline (2557.091 us; speedup 1.0000x reference)
//
#include <hip/hip_runtime.h>
#include <math.h>

#define DD 512
#define HEADS 8
#define DHD 64
#define MM 256
#define BB 8
#define CH 4
#define NCHUNK 2
#define NINST 6000
#define SIDE 78
#define PSIDE 84
#define NSQ 6084
#define NTOK 6085
#define PADF 59
#define NPAD 6144
#define LMM 24
#define RESK 33
#define MAXNN 520
#define KNN 12

typedef unsigned short u16;
typedef __attribute__((ext_vector_type(8))) short short8;
typedef __attribute__((ext_vector_type(4))) float f32x4;

__device__ __forceinline__ u16 f2bf(float f) {
    unsigned u = __float_as_uint(f);
    u += 0x7FFF + ((u >> 16) & 1);
    return (u16)(u >> 16);
}
__device__ __forceinline__ float bf2f(u16 v) {
    return __uint_as_float(((unsigned)v) << 16);
}

// async global->LDS, 16B per lane, wave-uniform LDS base
#define GLD_LDS16(src, dst) __builtin_amdgcn_global_load_lds( \
    (const __attribute__((address_space(1))) void*)(src),     \
    (__attribute__((address_space(3))) void*)(dst), 16, 0, 0)

// ---------------- reduction helpers (blockDim == 256 only) ----------------
__device__ __forceinline__ float blockReduceSum(float v, float* red) {
    int t = threadIdx.x;
    red[t] = v; __syncthreads();
    #pragma unroll
    for (int s = 128; s > 0; s >>= 1) { if (t < s) red[t] += red[t + s]; __syncthreads(); }
    float r = red[0]; __syncthreads();
    return r;
}
__device__ __forceinline__ float blockReduceMax(float v, float* red) {
    int t = threadIdx.x;
    red[t] = v; __syncthreads();
    #pragma unroll
    for (int s = 128; s > 0; s >>= 1) { if (t < s) red[t] = fmaxf(red[t], red[t + s]); __syncthreads(); }
    float r = red[0]; __syncthreads();
    return r;
}

// ---------------- diagnostic ----------------
__global__ void k_diag(float* __restrict__ out, float v) {
    int t = threadIdx.x;
    if (t < 32) out[t] = v;
}

// ---------------- weight transpose+convert: W[k][N] f32 -> Wt[n][512] bf16 ----------------
__global__ __launch_bounds__(256) void k_wconv(const float* __restrict__ W, int N, u16* __restrict__ Wt)
{
    __shared__ float tile[64][68];
    int n0 = blockIdx.x * 64, k0 = blockIdx.y * 64;
    int t = threadIdx.x;
    #pragma unroll
    for (int i = 0; i < 4; ++i) {
        int kr = (t >> 4) + i * 16, nc = (t & 15) * 4;
        *(float4*)&tile[kr][nc] = *(const float4*)&W[(size_t)(k0 + kr) * N + n0 + nc];
    }
    __syncthreads();
    int nr = t >> 2, kc = (t & 3) * 16;
    __align__(16) u16 tmp[16];
    #pragma unroll
    for (int j = 0; j < 16; ++j) tmp[j] = f2bf(tile[kc + j][nr]);
    *(uint4*)&Wt[(size_t)(n0 + nr) * 512 + k0 + kc]     = *(uint4*)&tmp[0];
    *(uint4*)&Wt[(size_t)(n0 + nr) * 512 + k0 + kc + 8] = *(uint4*)&tmp[8];
}

// ---------------- per-row LN stats ----------------
__global__ __launch_bounds__(256) void k_lnstat(const float* __restrict__ h, float* __restrict__ st) {
    __shared__ float red[256];
    int row = blockIdx.x;
    int t = threadIdx.x;
    const float* src = h + (size_t)row * 512;
    float x0 = src[t], x1 = src[t + 256];
    float mean = blockReduceSum(x0 + x1, red) * (1.f / 512.f);
    float d0 = x0 - mean, d1 = x1 - mean;
    float var = blockReduceSum(d0 * d0 + d1 * d1, red) * (1.f / 512.f);
    if (t == 0) { st[(size_t)row * 2] = mean; st[(size_t)row * 2 + 1] = 1.f / sqrtf(var + 1e-5f); }
}

// ---------------- LN'd + front-padded activations as bf16 (chunk-local) ----------------
__global__ __launch_bounds__(256) void k_lnbf(const float* __restrict__ h,
    const float* __restrict__ lnstat, const float* __restrict__ g,
    const float* __restrict__ be, int b0, u16* __restrict__ xp)
{
    int rowc = blockIdx.x;
    int b2 = rowc / NPAD, n2 = rowc - b2 * NPAD;
    int t = threadIdx.x;
    u16* dst = xp + (size_t)rowc * 512;
    int c = t * 2;
    if (n2 < PADF) { *(unsigned*)&dst[c] = 0u; return; }
    size_t ridx = (size_t)(b0 + b2) * NTOK + (n2 - PADF);
    const float* src = h + ridx * 512;
    float mu = lnstat[ridx * 2], rs = lnstat[ridx * 2 + 1];
    float v0 = (src[c] - mu) * rs * g[c] + be[c];
    float v1 = (src[c + 1] - mu) * rs * g[c + 1] + be[c + 1];
    u16 p[2] = { f2bf(v0), f2bf(v1) };
    *(unsigned*)&dst[c] = *(unsigned*)p;
}

// ---------------- MFMA bf16 GEMM, K=512, tile 128x128, BK=32; XCD swizzle ----------------
template<int MODE>
__global__ __launch_bounds__(256) void k_gemm(
    const float* __restrict__ A, const u16* __restrict__ A16,
    const u16* __restrict__ Wt, const float* __restrict__ bias,
    int rows, int b0,
    float* __restrict__ hbuf, u16* __restrict__ qb, u16* __restrict__ kb,
    u16* __restrict__ vb)
{
    __shared__ __align__(16) u16 As[128][32];
    __shared__ __align__(16) u16 Bs[128][32];
    int t = threadIdx.x;
    int nwg = gridDim.x * gridDim.y;
    int hid = blockIdx.y * gridDim.x + blockIdx.x;
    int per = nwg >> 3;
    int logical = (hid & 7) * per + (hid >> 3);
    int cx = logical % gridDim.x;
    int ry = logical / gridDim.x;
    int r0 = ry * 128, c0 = cx * 128;
    int w = t >> 6, l = t & 63, lr = l & 15, lg = l >> 4;

    int ch0  = w * 2;
    int crow0 = ch0 * 16 + (l >> 2);
    int ccol  = (l & 3) * 8;

    const u16* bsrc0 = Wt + (size_t)(c0 + crow0) * 512 + ccol;
    const u16* bsrc1 = bsrc0 + (size_t)16 * 512;

    const u16* asrc0 = nullptr; const u16* asrc1 = nullptr;
    if (MODE == 2) {
        asrc0 = A16 + (size_t)(r0 + crow0) * 512 + ccol;
        asrc1 = asrc0 + (size_t)16 * 512;
    } else if (MODE == 3) {
        int gr0 = r0 + crow0;
        int b20 = gr0 / NTOK, r20 = gr0 - b20 * NTOK;
        asrc0 = A16 + ((size_t)b20 * NPAD + r20 + PADF) * 512 + ccol;
        int gr1 = gr0 + 16;
        int b21 = gr1 / NTOK, r21 = gr1 - b21 * NTOK;
        asrc1 = A16 + ((size_t)b21 * NPAD + r21 + PADF) * 512 + ccol;
    }

    int srow = t >> 1, sks = (t & 1) * 16;
    int grow = r0 + srow;
    bool rowok = grow < rows;

    f32x4 acc[2][8];
    #pragma unroll
    for (int i = 0; i < 2; ++i)
        #pragma unroll
        for (int j = 0; j < 8; ++j) acc[i][j] = (f32x4){0.f, 0.f, 0.f, 0.f};

    for (int k0 = 0; k0 < 512; k0 += 32) {
        if (MODE == 1) {
            if (rowok) {
                __align__(16) u16 tmp[16];
                const float* src = A + (size_t)grow * 512 + k0 + sks;
                #pragma unroll
                for (int i = 0; i < 4; ++i) {
                    float4 v4 = *(const float4*)(src + i * 4);
                    tmp[i*4+0] = f2bf(v4.x); tmp[i*4+1] = f2bf(v4.y);
                    tmp[i*4+2] = f2bf(v4.z); tmp[i*4+3] = f2bf(v4.w);
                }
                *(uint4*)&As[srow][sks]     = *(uint4*)&tmp[0];
                *(uint4*)&As[srow][sks + 8] = *(uint4*)&tmp[8];
            } else {
                *(uint4*)&As[srow][sks]     = make_uint4(0, 0, 0, 0);
                *(uint4*)&As[srow][sks + 8] = make_uint4(0, 0, 0, 0);
            }
        } else {
            GLD_LDS16(asrc0 + k0, &As[ch0 * 16][0]);
            GLD_LDS16(asrc1 + k0, &As[ch0 * 16 + 16][0]);
        }
        GLD_LDS16(bsrc0 + k0, &Bs[ch0 * 16][0]);
        GLD_LDS16(bsrc1 + k0, &Bs[ch0 * 16 + 16][0]);
        __syncthreads();
        short8 a0 = *(const short8*)&As[w * 32 + lr][lg * 8];
        short8 a1 = *(const short8*)&As[w * 32 + 16 + lr][lg * 8];
        #pragma unroll
        for (int nf = 0; nf < 8; ++nf) {
            short8 bf = *(const short8*)&Bs[nf * 16 + lr][lg * 8];
            acc[0][nf] = __builtin_amdgcn_mfma_f32_16x16x32_bf16(a0, bf, acc[0][nf], 0, 0, 0);
            acc[1][nf] = __builtin_amdgcn_mfma_f32_16x16x32_bf16(a1, bf, acc[1][nf], 0, 0, 0);
        }
        __syncthreads();
    }
    #pragma unroll
    for (int mf = 0; mf < 2; ++mf) {
        #pragma unroll
        for (int r = 0; r < 4; ++r) {
            int row = r0 + w * 32 + mf * 16 + lg * 4 + r;
            if (row >= rows) continue;
            int b2, r2;
            if (MODE == 1)      { b2 = row / NINST; r2 = row - b2 * NINST; }
            else if (MODE == 2) { b2 = row / NPAD;  r2 = row - b2 * NPAD; }
            else                { b2 = row / NTOK;  r2 = row - b2 * NTOK; }
            #pragma unroll
            for (int nf = 0; nf < 8; ++nf) {
                int col = c0 + nf * 16 + lr;
                float val = acc[mf][nf][r];
                if (MODE == 1) {
                    val += bias[col];
                    val = fmaxf(val, 0.f);
                    hbuf[((size_t)b2 * NTOK + 1 + r2) * 512 + col] = val;
                } else if (MODE == 2) {
                    int which = col >> 9, head = (col >> 6) & 7, dh = col & 63;
                    u16* dst = which == 0 ? qb : (which == 1 ? kb : vb);
                    if (which == 0) val *= 0.125f;
                    dst[(((size_t)b2 * HEADS + head) * NPAD + r2) * 64 + dh] = f2bf(val);
                } else {
                    size_t o = ((size_t)(b0 + b2) * NTOK + r2) * 512 + col;
                    hbuf[o] += val + bias[col];
                }
            }
        }
    }
}

// ---------------- batched 256xNcols f32 GEMM (K=256), optional bf16 out ----------------
__global__ __launch_bounds__(256) void k_bgemm(
    const float* __restrict__ A, const float* __restrict__ B,
    float* __restrict__ C, u16* __restrict__ C16, int ncols, float coefA, float coefAB)
{
    __shared__ float As[16][68];
    __shared__ float Bs[16][68];
    int t = threadIdx.x;
    int bat = blockIdx.x, rt = blockIdx.y, ct = blockIdx.z;
    const float* Ab = A + (size_t)bat * 65536;
    const float* Bb = B + (size_t)bat * 256 * ncols;
    int r0 = rt * 64, c0 = ct * 64;
    int tr = t >> 4, tc = t & 15, lr = t >> 2, lk4 = (t & 3) << 2;
    int wkk = t >> 4, wcc = (t & 15) << 2;
    float acc[4][4] = {{0.f}};
    for (int k0 = 0; k0 < 256; k0 += 16) {
        float4 av = *(const float4*)(Ab + (size_t)(r0 + lr) * 256 + k0 + lk4);
        As[lk4 + 0][lr] = av.x;
        As[lk4 + 1][lr] = av.y;
        As[lk4 + 2][lr] = av.z;
        As[lk4 + 3][lr] = av.w;
        *(float4*)&Bs[wkk][wcc] = *(const float4*)(Bb + (size_t)(k0 + wkk) * ncols + c0 + wcc);
        __syncthreads();
        #pragma unroll
        for (int kk = 0; kk < 16; ++kk) {
            float a[4], b4[4];
            *(float4*)a  = *(float4*)&As[kk][tr << 2];
            *(float4*)b4 = *(float4*)&Bs[kk][tc << 2];
            #pragma unroll
            for (int i2 = 0; i2 < 4; ++i2)
                #pragma unroll
                for (int j2 = 0; j2 < 4; ++j2)
                    acc[i2][j2] += a[i2] * b4[j2];
        }
        __syncthreads();
    }
    #pragma unroll
    for (int i2 = 0; i2 < 4; ++i2) {
        int row = r0 + (tr << 2) + i2;
        #pragma unroll
        for (int j2 = 0; j2 < 4; ++j2) {
            int col = c0 + (tc << 2) + j2;
            float val = coefAB * acc[i2][j2];
            if (coefA != 0.f) val += coefA * Ab[(size_t)row * 256 + col];
            size_t o = (size_t)bat * 256 * ncols + (size_t)row * ncols + col;
            if (C16) C16[o] = f2bf(val);
            else     C[o] = val;
        }
    }
}

// ---------------- batched MFMA GEMM, bf16 in / bf16-or-f32 out (K=256, N=256) ----------------
__global__ __launch_bounds__(256) void k_bgemm_b16(
    const u16* __restrict__ A, const u16* __restrict__ B,
    u16* __restrict__ C, float* __restrict__ Cf, float coefA, float coefAB)
{
    __shared__ __align__(16) u16 As[64][40];
    __shared__ __align__(16) u16 Bs[64][40];
    int t = threadIdx.x;
    int bat = blockIdx.x, rt = blockIdx.y, ct = blockIdx.z;
    const u16* Ab = A + (size_t)bat * 65536;
    const u16* Bb = B + (size_t)bat * 65536;
    int r0 = rt * 64, c0 = ct * 64;
    int w = t >> 6, l = t & 63, lr = l & 15, lg = l >> 4;
    int am = t >> 2, ak = (t & 3) * 8;
    int bn = t & 63, bk0 = t >> 6 << 3;
    f32x4 acc[4];
    #pragma unroll
    for (int j = 0; j < 4; ++j) acc[j] = (f32x4){0.f, 0.f, 0.f, 0.f};
    for (int k0 = 0; k0 < 256; k0 += 32) {
        *(uint4*)&As[am][ak] = *(const uint4*)&Ab[(size_t)(r0 + am) * 256 + k0 + ak];
        __align__(16) u16 tb[8];
        #pragma unroll
        for (int i = 0; i < 8; ++i)
            tb[i] = Bb[(size_t)(k0 + bk0 + i) * 256 + c0 + bn];
        *(uint4*)&Bs[bn][bk0] = *(uint4*)&tb[0];
        __syncthreads();
        short8 a = *(const short8*)&As[w * 16 + lr][lg * 8];
        #pragma unroll
        for (int nf = 0; nf < 4; ++nf) {
            short8 bf = *(const short8*)&Bs[nf * 16 + lr][lg * 8];
            acc[nf] = __builtin_amdgcn_mfma_f32_16x16x32_bf16(a, bf, acc[nf], 0, 0, 0);
        }
        __syncthreads();
    }
    #pragma unroll
    for (int r = 0; r < 4; ++r) {
        int row = r0 + w * 16 + lg * 4 + r;
        #pragma unroll
        for (int nf = 0; nf < 4; ++nf) {
            int col = c0 + nf * 16 + lr;
            float val = coefAB * acc[nf][r];
            if (coefA != 0.f) val += coefA * bf2f(Ab[(size_t)row * 256 + col]);
            if (Cf) Cf[(size_t)bat * 65536 + (size_t)row * 256 + col] = val;
            else    C[(size_t)bat * 65536 + (size_t)row * 256 + col] = f2bf(val);
        }
    }
}

// ---------------- wrap rows + cls token ----------------
__global__ void k_fixup(float* __restrict__ h, const float* __restrict__ cls)
{
    int b = blockIdx.x, r = blockIdx.y, t = threadIdx.x;
    float* dst; const float* src;
    if (r < 84) {
        dst = h + ((size_t)b * NTOK + 6001 + r) * 512;
        src = h + ((size_t)b * NTOK + 1 + r) * 512;
    } else {
        dst = h + (size_t)b * NTOK * 512;
        src = cls;
    }
    dst[t] = src[t]; dst[t + 256] = src[t + 256];
}

// ---------------- landmarks (bf16 in, f32 + bf16 out) ----------------
__global__ void k_landmark(const u16* __restrict__ q, const u16* __restrict__ k,
                           float* __restrict__ q_l, float* __restrict__ k_l,
                           u16* __restrict__ k_l16)
{
    int bhm = blockIdx.x;
    int d = threadIdx.x;
    int bh = bhm >> 8, m = bhm & 255;
    const u16* qs = q + ((size_t)bh * NPAD + m * LMM) * 64 + d;
    const u16* ks = k + ((size_t)bh * NPAD + m * LMM) * 64 + d;
    float sq = 0.f, sk = 0.f;
    #pragma unroll
    for (int j = 0; j < LMM; ++j) { sq += bf2f(qs[(size_t)j * 64]); sk += bf2f(ks[(size_t)j * 64]); }
    float kv = sk * (1.f / 24.f);
    q_l[(size_t)bhm * 64 + d] = sq * (1.f / 24.f);
    k_l[(size_t)bhm * 64 + d] = kv;
    k_l16[(size_t)bhm * 64 + d] = f2bf(kv);
}

// ---------------- attn2 = softmax(q_l @ k_l^T), f32 + bf16 outputs ----------------
__global__ __launch_bounds__(256) void k_attn2(const float* __restrict__ q_l,
    const float* __restrict__ k_l, float* __restrict__ attn2, u16* __restrict__ a2b)
{
    __shared__ float ql[64];
    __shared__ float red[256];
    int bh = blockIdx.x >> 8, i = blockIdx.x & 255;
    int t = threadIdx.x;
    if (t < 64) ql[t] = q_l[((size_t)(bh * 256 + i)) * 64 + t];
    __syncthreads();
    const float4* kr = (const float4*)(k_l + ((size_t)bh * 256 + t) * 64);
    float s = 0.f;
    #pragma unroll
    for (int d4 = 0; d4 < 16; ++d4) {
        float4 kv = kr[d4];
        s += ql[d4 * 4] * kv.x + ql[d4 * 4 + 1] * kv.y + ql[d4 * 4 + 2] * kv.z + ql[d4 * 4 + 3] * kv.w;
    }
    float mx = blockReduceMax(s, red);
    float e = expf(s - mx);
    float S = blockReduceSum(e, red);
    float p = e / S;
    size_t o = ((size_t)(bh * 256 + i)) * 256 + t;
    attn2[o] = p;
    a2b[o] = f2bf(p);
}

// ---------------- pinv init -> bf16 ----------------
__global__ __launch_bounds__(256) void k_pinv_init(const float* __restrict__ x, u16* __restrict__ z16)
{
    __shared__ float red[256];
    int bh = blockIdx.x, t = threadIdx.x;
    const float* xb = x + (size_t)bh * 65536;
    float rs = 0.f;
    for (int j = 0; j < 256; ++j) rs += xb[t * 256 + j];
    float colv = blockReduceMax(rs, red);
    float cs = 0.f;
    for (int i2 = 0; i2 < 256; ++i2) cs += xb[i2 * 256 + t];
    float rowv = blockReduceMax(cs, red);
    float scale = 1.f / (colv * rowv);
    u16* zb = z16 + (size_t)bh * 65536;
    for (int i2 = 0; i2 < 256; ++i2)
        zb[(size_t)i2 * 256 + t] = f2bf(xb[(size_t)t * 256 + i2] * scale);
}

// ---------------- attn3 @ v : flash MFMA-bf16 partial kernel (bf16 K/V) ----------------
__global__ __launch_bounds__(256) void k_attn3_part(
    const float* __restrict__ q_l, const u16* __restrict__ kbuf,
    const u16* __restrict__ vbuf, float* __restrict__ pv, float* __restrict__ pstat)
{
    __shared__ __align__(16) u16 Qb[64][72];
    __shared__ __align__(16) u16 Kb[64][72];
    __shared__ __align__(16) u16 Pb[64][72];
    int bh = blockIdx.x, mb = blockIdx.y, ns = blockIdx.z;
    int t = threadIdx.x, w = t >> 6, l = t & 63, lr = l & 15, lg = l >> 4;
    {
        int srow = t >> 2, sd = (t & 3) * 16;
        const float* src = q_l + ((size_t)bh * 256 + mb * 64 + srow) * 64 + sd;
        __align__(16) u16 tmp[16];
        #pragma unroll
        for (int i = 0; i < 16; ++i) tmp[i] = f2bf(src[i]);
        *(uint4*)&Qb[srow][sd]     = *(uint4*)&tmp[0];
        *(uint4*)&Qb[srow][sd + 8] = *(uint4*)&tmp[8];
    }
    f32x4 acc[4];
    #pragma unroll
    for (int j = 0; j < 4; ++j) acc[j] = (f32x4){0.f, 0.f, 0.f, 0.f};
    float m_run[4], s_run[4];
    #pragma unroll
    for (int i = 0; i < 4; ++i) { m_run[i] = -INFINITY; s_run[i] = 0.f; }
    const int n00 = ns * 768;
    for (int tile = 0; tile < 12; ++tile) {
        int nb = n00 + tile * 64;
        __syncthreads();
        {
            int srow = t >> 2, sd = (t & 3) * 16;
            const u16* src = kbuf + ((size_t)bh * NPAD + nb + srow) * 64 + sd;
            *(uint4*)&Kb[srow][sd]     = *(const uint4*)&src[0];
            *(uint4*)&Kb[srow][sd + 8] = *(const uint4*)&src[8];
        }
        __syncthreads();
        f32x4 s[4];
        #pragma unroll
        for (int j = 0; j < 4; ++j) s[j] = (f32x4){0.f, 0.f, 0.f, 0.f};
        #pragma unroll
        for (int ks = 0; ks < 64; ks += 32) {
            short8 a = *(const short8*)&Qb[w * 16 + lr][lg * 8 + ks];
            #pragma unroll
            for (int nf = 0; nf < 4; ++nf) {
                short8 bf = *(const short8*)&Kb[nf * 16 + lr][lg * 8 + ks];
                s[nf] = __builtin_amdgcn_mfma_f32_16x16x32_bf16(a, bf, s[nf], 0, 0, 0);
            }
        }
        #pragma unroll
        for (int r = 0; r < 4; ++r) {
            float lm = fmaxf(fmaxf(s[0][r], s[1][r]), fmaxf(s[2][r], s[3][r]));
            #pragma unroll
            for (int off = 1; off < 16; off <<= 1)
                lm = fmaxf(lm, __shfl_xor(lm, off, 16));
            float m_new = fmaxf(m_run[r], lm);
            float scf = expf(m_run[r] - m_new);
            s_run[r] *= scf;
            acc[0][r] *= scf; acc[1][r] *= scf; acc[2][r] *= scf; acc[3][r] *= scf;
            float p0 = expf(s[0][r] - m_new), p1 = expf(s[1][r] - m_new);
            float p2 = expf(s[2][r] - m_new), p3 = expf(s[3][r] - m_new);
            float ls = p0 + p1 + p2 + p3;
            #pragma unroll
            for (int off = 1; off < 16; off <<= 1)
                ls += __shfl_xor(ls, off, 16);
            s_run[r] += ls;
            m_run[r] = m_new;
            int prow = w * 16 + lg * 4 + r;
            Pb[prow][lr]      = f2bf(p0);
            Pb[prow][16 + lr] = f2bf(p1);
            Pb[prow][32 + lr] = f2bf(p2);
            Pb[prow][48 + lr] = f2bf(p3);
        }
        __syncthreads();
        {
            int nl = t & 63, dvb = (t >> 6) * 16;
            const u16* src = vbuf + ((size_t)bh * NPAD + nb + nl) * 64 + dvb;
            __align__(16) u16 tmp[16];
            *(uint4*)&tmp[0] = *(const uint4*)&src[0];
            *(uint4*)&tmp[8] = *(const uint4*)&src[8];
            #pragma unroll
            for (int j = 0; j < 16; ++j) Kb[dvb + j][nl] = tmp[j];
        }
        __syncthreads();
        #pragma unroll
        for (int ks = 0; ks < 64; ks += 32) {
            short8 a = *(const short8*)&Pb[w * 16 + lr][lg * 8 + ks];
            #pragma unroll
            for (int df = 0; df < 4; ++df) {
                short8 bf = *(const short8*)&Kb[df * 16 + lr][lg * 8 + ks];
                acc[df] = __builtin_amdgcn_mfma_f32_16x16x32_bf16(a, bf, acc[df], 0, 0, 0);
            }
        }
    }
    #pragma unroll
    for (int r = 0; r < 4; ++r) {
        int mloc = w * 16 + lg * 4 + r;
        size_t row = (size_t)bh * 256 + mb * 64 + mloc;
        float* dst = pv + (row * 8 + ns) * 64;
        dst[lr]      = acc[0][r];
        dst[16 + lr] = acc[1][r];
        dst[32 + lr] = acc[2][r];
        dst[48 + lr] = acc[3][r];
        if (lr == 0) { pstat[row * 16 + ns * 2] = m_run[r]; pstat[row * 16 + ns * 2 + 1] = s_run[r]; }
    }
}

// combine 8 slices -> out3
__global__ __launch_bounds__(256) void k_attn3_comb(
    const float* __restrict__ pv, const float* __restrict__ pstat, float* __restrict__ out3)
{
    size_t row = (size_t)blockIdx.x * 4 + (threadIdx.x >> 6);
    int d = threadIdx.x & 63;
    float M = -INFINITY;
    #pragma unroll
    for (int s = 0; s < 8; ++s) M = fmaxf(M, pstat[row * 16 + s * 2]);
    float num = 0.f, den = 0.f;
    #pragma unroll
    for (int s = 0; s < 8; ++s) {
        float w = expf(pstat[row * 16 + s * 2] - M);
        den += w * pstat[row * 16 + s * 2 + 1];
        num += w * pv[(row * 8 + s) * 64 + d];
    }
    out3[row * 64 + d] = num / den;
}

// ---------------- attn1 softmax @ w2 + res conv + res_b; bf16 bufv, 31KB LDS ----------------
__global__ __launch_bounds__(256) void k_attn1res(
    const u16* __restrict__ qbuf, const u16* __restrict__ k_l16,
    const u16* __restrict__ w216, const u16* __restrict__ vbuf,
    const float* __restrict__ res_w, const float* __restrict__ res_b,
    u16* __restrict__ outb16)
{
    __shared__ __align__(16) char smem[31232];
    u16 (*Qb)[72]   = (u16(*)[72])smem;
    u16 (*Kb)[72]   = (u16(*)[72])(smem + 9216);
    u16 (*Pb)[72]   = (u16(*)[72])(smem + 18432);
    float (*osm)[68] = (float(*)[68])smem;
    u16 (*bufv)[72]  = (u16(*)[72])(smem + 17408);
    __shared__ float wconv[RESK];
    int bh = blockIdx.x, nb = blockIdx.y, hh = bh & 7;
    int b2 = bh >> 3;
    int t = threadIdx.x, w = t >> 6, l = t & 63, lr = l & 15, lg = l >> 4;
    int tr = t >> 4, tc = t & 15;
    int n0 = nb * 64;
    if (t < RESK) wconv[t] = res_w[hh * RESK + t];
    {
        int srow = t >> 2, sd = (t & 3) * 16;
        const u16* src = qbuf + ((size_t)bh * NPAD + n0 + srow) * 64 + sd;
        *(uint4*)&Qb[srow][sd]     = *(const uint4*)&src[0];
        *(uint4*)&Qb[srow][sd + 8] = *(const uint4*)&src[8];
    }
    f32x4 acc[4];
    #pragma unroll
    for (int j = 0; j < 4; ++j) acc[j] = (f32x4){0.f, 0.f, 0.f, 0.f};
    float m_run[4], s_run[4];
    #pragma unroll
    for (int i = 0; i < 4; ++i) { m_run[i] = -INFINITY; s_run[i] = 0.f; }
    for (int mt = 0; mt < 4; ++mt) {
        __syncthreads();
        {
            int srow = t >> 2, sd = (t & 3) * 16;
            const u16* src = k_l16 + ((size_t)bh * 256 + mt * 64 + srow) * 64 + sd;
            *(uint4*)&Kb[srow][sd]     = *(const uint4*)&src[0];
            *(uint4*)&Kb[srow][sd + 8] = *(const uint4*)&src[8];
        }
        __syncthreads();
        f32x4 s[4];
        #pragma unroll
        for (int j = 0; j < 4; ++j) s[j] = (f32x4){0.f, 0.f, 0.f, 0.f};
        #pragma unroll
        for (int ks = 0; ks < 64; ks += 32) {
            short8 a = *(const short8*)&Qb[w * 16 + lr][lg * 8 + ks];
            #pragma unroll
            for (int nf = 0; nf < 4; ++nf) {
                short8 bf = *(const short8*)&Kb[nf * 16 + lr][lg * 8 + ks];
                s[nf] = __builtin_amdgcn_mfma_f32_16x16x32_bf16(a, bf, s[nf], 0, 0, 0);
            }
        }
        #pragma unroll
        for (int r = 0; r < 4; ++r) {
            float lm = fmaxf(fmaxf(s[0][r], s[1][r]), fmaxf(s[2][r], s[3][r]));
            #pragma unroll
            for (int off = 1; off < 16; off <<= 1)
                lm = fmaxf(lm, __shfl_xor(lm, off, 16));
            float m_new = fmaxf(m_run[r], lm);
            float scf = expf(m_run[r] - m_new);
            s_run[r] *= scf;
            acc[0][r] *= scf; acc[1][r] *= scf; acc[2][r] *= scf; acc[3][r] *= scf;
            float p0 = expf(s[0][r] - m_new), p1 = expf(s[1][r] - m_new);
            float p2 = expf(s[2][r] - m_new), p3 = expf(s[3][r] - m_new);
            float ls = p0 + p1 + p2 + p3;
            #pragma unroll
            for (int off = 1; off < 16; off <<= 1)
                ls += __shfl_xor(ls, off, 16);
            s_run[r] += ls;
            m_run[r] = m_new;
            int prow = w * 16 + lg * 4 + r;
            Pb[prow][lr]      = f2bf(p0);
            Pb[prow][16 + lr] = f2bf(p1);
            Pb[prow][32 + lr] = f2bf(p2);
            Pb[prow][48 + lr] = f2bf(p3);
        }
        __syncthreads();
        {
            int nl = t & 63, dvb = (t >> 6) * 16;
            const u16* src = w216 + ((size_t)bh * 256 + mt * 64 + nl) * 64 + dvb;
            __align__(16) u16 tmp[16];
            *(uint4*)&tmp[0] = *(const uint4*)&src[0];
            *(uint4*)&tmp[8] = *(const uint4*)&src[8];
            #pragma unroll
            for (int j = 0; j < 16; ++j) Kb[dvb + j][nl] = tmp[j];
        }
        __syncthreads();
        #pragma unroll
        for (int ks = 0; ks < 64; ks += 32) {
            short8 a = *(const short8*)&Pb[w * 16 + lr][lg * 8 + ks];
            #pragma unroll
            for (int df = 0; df < 4; ++df) {
                short8 bf = *(const short8*)&Kb[df * 16 + lr][lg * 8 + ks];
                acc[df] = __builtin_amdgcn_mfma_f32_16x16x32_bf16(a, bf, acc[df], 0, 0, 0);
            }
        }
    }
    __syncthreads();
    #pragma unroll
    for (int r = 0; r < 4; ++r) {
        float inv = 1.f / s_run[r];
        int m = w * 16 + lg * 4 + r;
        osm[m][lr]      = acc[0][r] * inv;
        osm[m][16 + lr] = acc[1][r] * inv;
        osm[m][32 + lr] = acc[2][r] * inv;
        osm[m][48 + lr] = acc[3][r] * inv;
    }
    for (int idx = t; idx < 96 * 8; idx += 256) {
        int rowl = idx >> 3, d8 = (idx & 7) * 8;
        int gn = n0 - 16 + rowl;
        uint4 v4 = make_uint4(0u, 0u, 0u, 0u);
        if (gn >= 0 && gn < NPAD)
            v4 = *(const uint4*)(vbuf + ((size_t)bh * NPAD + gn) * 64 + d8);
        *(uint4*)&bufv[rowl][d8] = v4;
    }
    __syncthreads();
    float rb = res_b[hh];
    #pragma unroll
    for (int i = 0; i < 4; ++i) {
        int rl = tr * 4 + i;
        int n = n0 + rl;
        if (n < PADF) continue;
        float4 oo = *(float4*)&osm[rl][tc * 4];
        float o0 = oo.x, o1 = oo.y, o2 = oo.z, o3 = oo.w;
        #pragma unroll
        for (int jj = 0; jj < RESK; ++jj) {
            float wj = wconv[jj];
            u16 q4[4];
            *(uint2*)q4 = *(const uint2*)&bufv[rl + jj][tc * 4];
            o0 += wj * bf2f(q4[0]); o1 += wj * bf2f(q4[1]);
            o2 += wj * bf2f(q4[2]); o3 += wj * bf2f(q4[3]);
        }
        u16 ob[4] = { f2bf(o0 + rb), f2bf(o1 + rb), f2bf(o2 + rb), f2bf(o3 + rb) };
        u16* dst = outb16 + ((size_t)b2 * NPAD + n) * 512 + hh * 64 + tc * 4;
        *(uint2*)dst = *(uint2*)ob;
    }
}

// ---------------- PPEG via transpose ----------------
__global__ __launch_bounds__(256) void k_tr_fwd(const float* __restrict__ h, float* __restrict__ ft)
{
    __shared__ float tile[64][68];
    int tt = blockIdx.x, ct8 = blockIdx.y, b = blockIdx.z;
    int t = threadIdx.x;
    int p0 = tt * 64, c0 = ct8 * 64;
    #pragma unroll
    for (int i = 0; i < 4; ++i) {
        int plr = (t >> 4) + i * 16;
        int cl = (t & 15) * 4;
        int p = p0 + plr;
        if (p < NSQ) {
            float4 v = *(const float4*)(h + ((size_t)b * NTOK + 1 + p) * 512 + c0 + cl);
            *(float4*)&tile[plr][cl] = v;
        }
    }
    __syncthreads();
    #pragma unroll
    for (int i = 0; i < 4; ++i) {
        int cl = (t >> 4) + i * 16;
        int plr = (t & 15) * 4;
        if (p0 + plr + 3 < NSQ) {
            float4 v = make_float4(tile[plr][cl], tile[plr + 1][cl], tile[plr + 2][cl], tile[plr + 3][cl]);
            *(float4*)(ft + ((size_t)b * 512 + c0 + cl) * NSQ + p0 + plr) = v;
        }
    }
}

__global__ __launch_bounds__(256) void k_tr_bwd(const float* __restrict__ ft, float* __restrict__ h)
{
    __shared__ float tile[64][68];
    int tt = blockIdx.x, ct8 = blockIdx.y, b = blockIdx.z;
    int t = threadIdx.x;
    int p0 = tt * 64, c0 = ct8 * 64;
    #pragma unroll
    for (int i = 0; i < 4; ++i) {
        int cl = (t >> 4) + i * 16;
        int plr = (t & 15) * 4;
        if (p0 + plr + 3 < NSQ) {
            float4 v = *(const float4*)(ft + ((size_t)b * 512 + c0 + cl) * NSQ + p0 + plr);
            tile[plr][cl] = v.x; tile[plr + 1][cl] = v.y;
            tile[plr + 2][cl] = v.z; tile[plr + 3][cl] = v.w;
        }
    }
    __syncthreads();
    #pragma unroll
    for (int i = 0; i < 4; ++i) {
        int plr = (t >> 4) + i * 16;
        int cl = (t & 15) * 4;
        int p = p0 + plr;
        if (p < NSQ) {
            float4 v = *(float4*)&tile[plr][cl];
            *(float4*)(h + ((size_t)b * NTOK + 1 + p) * 512 + c0 + cl) = v;
        }
    }
}

// per (b, channel) plane: combined 7x7 weights, register-blocked 4 outputs/thread
__global__ __launch_bounds__(256) void k_ppeg_t(float* __restrict__ ft,
    const float* __restrict__ w7, const float* __restrict__ b7,
    const float* __restrict__ w5, const float* __restrict__ b5,
    const float* __restrict__ w3, const float* __restrict__ b3)
{
    __shared__ __align__(16) float f[PSIDE * PSIDE];
    __shared__ float wt[49];
    int bc = blockIdx.x;
    int b = bc >> 9, c = bc & 511;
    int t = threadIdx.x;
    float* plane = ft + ((size_t)b * 512 + c) * NSQ;
    for (int i = t; i < PSIDE * PSIDE; i += 256) f[i] = 0.f;
    if (t < 49) {
        int dy = t / 7 - 3, dx = t % 7 - 3;
        float v = w7[c * 49 + t];
        if (dy >= -2 && dy <= 2 && dx >= -2 && dx <= 2) v += w5[c * 25 + (dy + 2) * 5 + (dx + 2)];
        if (dy >= -1 && dy <= 1 && dx >= -1 && dx <= 1) v += w3[c * 9 + (dy + 1) * 3 + (dx + 1)];
        wt[t] = v;
    }
    __syncthreads();
    for (int p = t; p < NSQ; p += 256) {
        int r = p / SIDE, s2 = p - r * SIDE;
        f[(r + 3) * PSIDE + s2 + 3] = plane[p];
    }
    __syncthreads();
    float bsum = b7[c] + b5[c] + b3[c];
    for (int st = t; st < SIDE * 20; st += 256) {
        int r = st / 20, s0 = (st - (st / 20) * 20) * 4;
        float a0 = bsum + f[(r + 3) * PSIDE + s0 + 3];
        float a1 = bsum + f[(r + 3) * PSIDE + s0 + 4];
        float a2 = bsum + f[(r + 3) * PSIDE + s0 + 5];
        float a3 = bsum + f[(r + 3) * PSIDE + s0 + 6];
        #pragma unroll
        for (int dyy = 0; dyy < 7; ++dyy) {
            const float* rowp = &f[(r + dyy) * PSIDE + s0];
            float win[12];
            *(float4*)&win[0] = *(const float4*)&rowp[0];
            *(float4*)&win[4] = *(const float4*)&rowp[4];
            *(float4*)&win[8] = *(const float4*)&rowp[8];
            const float* wr = &wt[dyy * 7];
            #pragma unroll
            for (int dxx = 0; dxx < 7; ++dxx) {
                float wj = wr[dxx];
                a0 += win[0 + dxx] * wj;
                a1 += win[1 + dxx] * wj;
                a2 += win[2 + dxx] * wj;
                a3 += win[3 + dxx] * wj;
            }
        }
        int base = r * SIDE + s0;
        plane[base] = a0;
        if (s0 + 1 < SIDE) plane[base + 1] = a1;
        if (s0 + 2 < SIDE) plane[base + 2] = a2;
        if (s0 + 3 < SIDE) plane[base + 3] = a3;
    }
}

// ---------------- final LN of cls token ----------------
__global__ __launch_bounds__(256) void k_bag(const float* __restrict__ h,
    const float* __restrict__ g, const float* __restrict__ be, float* __restrict__ bag)
{
    __shared__ float red[256];
    int b = blockIdx.x, t = threadIdx.x;
    const float* src = h + (size_t)b * NTOK * 512;
    float x0 = src[t], x1 = src[t + 256];
    float mean = blockReduceSum(x0 + x1, red) * (1.f / 512.f);
    float d0 = x0 - mean, d1 = x1 - mean;
    float var = blockReduceSum(d0 * d0 + d1 * d1, red) * (1.f / 512.f);
    float rs = 1.f / sqrtf(var + 1e-5f);
    bag[b * 512 + t]       = d0 * rs * g[t] + be[t];
    bag[b * 512 + t + 256] = d1 * rs * g[t + 256] + be[t + 256];
}

__global__ void k_mlp(const float* __restrict__ bag, const float* __restrict__ fc2w,
                      const float* __restrict__ fc2b, float* __restrict__ out)
{
    int t = threadIdx.x;
    if (t < 16) {
        int b = t >> 1, c = t & 1;
        float val = fc2b[c];
        for (int k2 = 0; k2 < 512; ++k2) val += bag[b * 512 + k2] * fc2w[k2 * 2 + c];
        out[b * 2 + c] = val;
    }
}

__global__ __launch_bounds__(256) void k_xcat(const float* __restrict__ bag,
    const float* __restrict__ reh, float* __restrict__ xn)
{
    __shared__ float red[256];
    int i = blockIdx.x, t = threadIdx.x;
    const float* src = (i < BB) ? (bag + (size_t)i * 512) : (reh + (size_t)(i - BB) * 512);
    float x0 = src[t], x1 = src[t + 256];
    float nrm = sqrtf(blockReduceSum(x0 * x0 + x1 * x1, red));
    float inv = 1.f / (nrm + 1e-8f);
    xn[(size_t)i * 512 + t]       = x0 * inv;
    xn[(size_t)i * 512 + t + 256] = x1 * inv;
}

// ---------------- sim row + top-12 (4-acc ILP dot + wave-shfl argmax) ----------------
__global__ __launch_bounds__(256) void k_sim_topk(const float* __restrict__ xn,
    int* __restrict__ idxb, float* __restrict__ wgt, float* __restrict__ dinvb)
{
    __shared__ float xi[512];
    __shared__ float s[MAXNN];
    __shared__ float wv[4];
    __shared__ int wi_[4];
    int i = blockIdx.x, t = threadIdx.x;
    xi[t] = xn[(size_t)i * 512 + t];
    xi[t + 256] = xn[(size_t)i * 512 + t + 256];
    __syncthreads();
    for (int j = t; j < MAXNN; j += 256) {
        const float4* xj = (const float4*)(xn + (size_t)j * 512);
        float a0 = 0.f, a1 = 0.f, a2 = 0.f, a3 = 0.f;
        for (int d4 = 0; d4 < 128; d4 += 4) {
            float4 v0 = xj[d4], v1 = xj[d4 + 1], v2 = xj[d4 + 2], v3 = xj[d4 + 3];
            const float* x0 = &xi[d4 * 4];
            a0 += x0[0]  * v0.x + x0[1]  * v0.y + x0[2]  * v0.z + x0[3]  * v0.w;
            a1 += x0[4]  * v1.x + x0[5]  * v1.y + x0[6]  * v1.z + x0[7]  * v1.w;
            a2 += x0[8]  * v2.x + x0[9]  * v2.y + x0[10] * v2.z + x0[11] * v2.w;
            a3 += x0[12] * v3.x + x0[13] * v3.y + x0[14] * v3.z + x0[15] * v3.w;
        }
        float dot = (a0 + a1) + (a2 + a3);
        s[j] = dot - (j == i ? 1e9f : 0.f);
    }
    __syncthreads();
    float degsum = 0.f;
    for (int kk = 0; kk < KNN; ++kk) {
        float bv = -INFINITY; int bi = MAXNN;
        for (int j = t; j < MAXNN; j += 256) {
            float vv = s[j];
            if (vv > bv) { bv = vv; bi = j; }
        }
        // 64-lane wave argmax (smaller index wins ties)
        #pragma unroll
        for (int off = 32; off > 0; off >>= 1) {
            float ov = __shfl_down(bv, off);
            int   oi = __shfl_down(bi, off);
            if (ov > bv || (ov == bv && oi < bi)) { bv = ov; bi = oi; }
        }
        if ((t & 63) == 0) { wv[t >> 6] = bv; wi_[t >> 6] = bi; }
        __syncthreads();
        if (t == 0) {
            bv = wv[0]; bi = wi_[0];
            #pragma unroll
            for (int q = 1; q < 4; ++q)
                if (wv[q] > bv || (wv[q] == bv && wi_[q] < bi)) { bv = wv[q]; bi = wi_[q]; }
            idxb[i * KNN + kk] = bi;
            float ww = fmaxf(bv, 0.f);
            wgt[i * KNN + kk] = ww;
            degsum += ww;
            s[bi] = -INFINITY;
            if (kk == KNN - 1) dinvb[i] = 1.f / sqrtf(1.f + degsum);
        }
        __syncthreads();
    }
}

// ---------------- GCN ----------------
__global__ __launch_bounds__(256) void k_hh1(const float* __restrict__ bag,
    const float* __restrict__ w1, float* __restrict__ hh1)
{
    int i = blockIdx.x, t = threadIdx.x;
    if (i >= BB) { hh1[(size_t)i * 256 + t] = 0.f; return; }
    float acc = 0.f;
    for (int k2 = 0; k2 < 512; ++k2) acc += bag[i * 512 + k2] * w1[(size_t)k2 * 256 + t];
    hh1[(size_t)i * 256 + t] = acc;
}

__global__ __launch_bounds__(256) void k_g1(const float* __restrict__ hh1,
    const int* __restrict__ idxb, const float* __restrict__ wgt,
    const float* __restrict__ dinvb, const float* __restrict__ b1, float* __restrict__ g)
{
    __shared__ float cf[KNN];
    __shared__ int src[KNN];
    int i = blockIdx.x, t = threadIdx.x;
    if (t < KNN) {
        int s2 = idxb[i * KNN + t];
        src[t] = s2;
        cf[t] = wgt[i * KNN + t] * dinvb[s2] * dinvb[i];
    }
    __syncthreads();
    float di = dinvb[i];
    float val = hh1[(size_t)i * 256 + t] * di * di + b1[t];
    #pragma unroll
    for (int e = 0; e < KNN; ++e) val += cf[e] * hh1[(size_t)src[e] * 256 + t];
    g[(size_t)i * 256 + t] = fmaxf(val, 0.f);
}

__global__ __launch_bounds__(256) void k_hh2(const float* __restrict__ g,
    const float* __restrict__ w2g, float* __restrict__ hh2)
{
    __shared__ float red[256];
    int i = blockIdx.x, t = threadIdx.x;
    float gg = g[(size_t)i * 256 + t];
    float s0 = blockReduceSum(gg * w2g[t * 2 + 0], red);
    float s1 = blockReduceSum(gg * w2g[t * 2 + 1], red);
    if (t == 0) { hh2[i * 2 + 0] = s0; hh2[i * 2 + 1] = s1; }
}

__global__ void k_gout(const float* __restrict__ hh2, const int* __restrict__ idxb,
    const float* __restrict__ wgt, const float* __restrict__ dinvb,
    const float* __restrict__ b2, float* __restrict__ out)
{
    int t = threadIdx.x;
    if (t < 16) {
        int i = t >> 1, c = t & 1;
        float di = dinvb[i];
        float val = hh2[i * 2 + c] * di * di + b2[c];
        for (int e = 0; e < KNN; ++e) {
            int s2 = idxb[i * KNN + e];
            val += wgt[i * KNN + e] * dinvb[s2] * di * hh2[s2 * 2 + c];
        }
        out[16 + i * 2 + c] = val;
    }
}

extern "C" void kernel_launch(void* const* d_in, const int* in_sizes, int n_in,
                              void* d_out, int out_size, void* d_ws, size_t ws_size,
                              hipStream_t stream)
{
    (void)in_sizes; (void)n_in; (void)out_size;
    const float* x     = (const float*)d_in[0];
    const float* fc1_w = (const float*)d_in[1];
    const float* fc1_b = (const float*)d_in[2];
    const float* cls   = (const float*)d_in[3];
    const float* lp[2][7];
    for (int l = 0; l < 2; ++l)
        for (int j = 0; j < 7; ++j)
            lp[l][j] = (const float*)d_in[4 + l * 7 + j];
    const float* w7 = (const float*)d_in[18]; const float* b7 = (const float*)d_in[19];
    const float* w5 = (const float*)d_in[20]; const float* b5 = (const float*)d_in[21];
    const float* w3 = (const float*)d_in[22]; const float* b3 = (const float*)d_in[23];
    const float* lnf_g = (const float*)d_in[24]; const float* lnf_b = (const float*)d_in[25];
    const float* fc2w = (const float*)d_in[26]; const float* fc2b = (const float*)d_in[27];
    const float* gw1 = (const float*)d_in[28]; const float* gb1 = (const float*)d_in[29];
    const float* gw2 = (const float*)d_in[30]; const float* gb2 = (const float*)d_in[31];
    const float* reh = (const float*)d_in[32];
    float* out = (float*)d_out;

    // Workspace budget: 92,943,144 floats = 371,772,576 bytes (ws has 376 MiB).
    const size_t REQUIRED = 92943144ull * 4ull;
    if (ws_size < REQUIRED) {
        k_diag<<<1, 32, 0, stream>>>(out, (float)ws_size);
        return;
    }

    float* Wf = (float*)d_ws;
    size_t off = 0;
    auto alloc = [&](size_t n) { float* p = Wf + off; off += n; return p; };
    float* h      = alloc((size_t)BB * NTOK * 512);
    float* lnstat = alloc((size_t)BB * NTOK * 2);
    u16* q16 = (u16*)alloc(12582912);   // BB*NPAD*512 u16 (full batch); ft overlay here
    u16* k16 = (u16*)alloc(6291456);    // CH*NPAD*512 u16 (chunk-local)
    u16* v16 = (u16*)alloc(12582912);   // full batch
    float* q_l  = alloc((size_t)CH * HEADS * 256 * 64);   // chunk-local
    float* k_l  = alloc((size_t)CH * HEADS * 256 * 64);   // chunk-local
    float* out3 = alloc((size_t)BB * HEADS * 256 * 64);   // both chunks
    u16* k_l16  = (u16*)alloc(524288);   // both chunks (1,048,576 u16)
    u16* w216   = (u16*)alloc(524288);   // both chunks
    float* bag  = alloc(8 * 512);
    float* xn   = alloc((size_t)MAXNN * 512);
    float* hh1  = alloc((size_t)MAXNN * 256);
    float* gbuf = alloc((size_t)MAXNN * 256);
    float* hh2  = alloc(MAXNN * 2);
    float* dinv = alloc(MAXNN);
    float* wgt  = alloc(MAXNN * KNN);
    int*   idxb = (int*)alloc(MAXNN * KNN);
    float* pvp   = alloc((size_t)32 * 256 * 8 * 64);
    float* pstat = alloc((size_t)32 * 256 * 16);
    float* attn2f = alloc(4194304);      // 64 batches x 65536 f32
    float* zF2    = alloc(4194304);      // 64 batches x 65536 f32
    u16* xp16  = (u16*)alloc(3145728);
    u16* at16  = (u16*)alloc(3145728);
    u16* a2b   = (u16*)alloc(2097152);   // 64 x 65536 u16
    u16* z16A  = (u16*)alloc(2097152);
    u16* z16B  = (u16*)alloc(2097152);
    u16* xz16  = (u16*)alloc(2097152);
    u16* p116  = (u16*)alloc(2097152);
    u16* p216  = (u16*)alloc(2097152);
    u16* fc1t  = (u16*)alloc(131072);
    u16* qkvt0 = (u16*)alloc(393216);
    u16* outt0 = (u16*)alloc(131072);
    u16* qkvt1 = (u16*)alloc(393216);
    u16* outt1 = (u16*)alloc(131072);

    // PPEG ft (24.92M f32) overlays q16+k16+v16 span (31.46M f32) — dead between layers
    float* ft = (float*)q16;
    const size_t QVOFF = (size_t)CH * HEADS * NPAD * 64;      // 12,582,912 u16 per chunk (q/v)
    const size_t LOFF  = (size_t)CH * HEADS * 256 * 64;       // 524,288 per chunk (k_l16/w216/out3)
    const size_t A2OFF = (size_t)32 * 65536;                  // per chunk (attn2/a2b)

    // preconvert/transpose all weights to bf16
    k_wconv<<<dim3(8, 8), 256, 0, stream>>>(fc1_w, 512, fc1t);
    k_wconv<<<dim3(24, 8), 256, 0, stream>>>(lp[0][2], 1536, qkvt0);
    k_wconv<<<dim3(8, 8), 256, 0, stream>>>(lp[0][3], 512, outt0);
    k_wconv<<<dim3(24, 8), 256, 0, stream>>>(lp[1][2], 1536, qkvt1);
    k_wconv<<<dim3(8, 8), 256, 0, stream>>>(lp[1][3], 512, outt1);

    // fc1 + relu -> h rows 1..6000, then wrap rows + cls
    k_gemm<1><<<dim3(4, 376), 256, 0, stream>>>(x, nullptr, fc1t, fc1_b, BB * NINST, 0,
                                                h, nullptr, nullptr, nullptr);
    k_fixup<<<dim3(BB, 85), 256, 0, stream>>>(h, cls);

    for (int l = 0; l < 2; ++l) {
        const float* ln_g  = lp[l][0];
        const float* ln_b  = lp[l][1];
        const u16* qkvt    = l == 0 ? qkvt0 : qkvt1;
        const u16* outt    = l == 0 ? outt0 : outt1;
        const float* out_b = lp[l][4];
        const float* res_w = lp[l][5];
        const float* res_b = lp[l][6];

        k_lnstat<<<BB * NTOK, 256, 0, stream>>>(h, lnstat);
        // phase A: per chunk qkv + attn3 + attn2
        for (int c = 0; c < NCHUNK; ++c) {
            int b0 = c * CH;
            k_lnbf<<<CH * NPAD, 256, 0, stream>>>(h, lnstat, ln_g, ln_b, b0, xp16);
            k_gemm<2><<<dim3(12, 192), 256, 0, stream>>>(nullptr, xp16, qkvt, nullptr, CH * NPAD, b0,
                                                         nullptr, q16 + c * QVOFF, k16, v16 + c * QVOFF);
            k_landmark<<<32 * 256, 64, 0, stream>>>(q16 + c * QVOFF, k16, q_l, k_l, k_l16 + c * LOFF);
            k_attn3_part<<<dim3(32, 4, 8), 256, 0, stream>>>(q_l, k16, v16 + c * QVOFF, pvp, pstat);
            k_attn3_comb<<<2048, 256, 0, stream>>>(pvp, pstat, out3 + c * LOFF);
            k_attn2<<<32 * 256, 256, 0, stream>>>(q_l, k_l, attn2f + c * A2OFF, a2b + c * A2OFF);
        }
        // batched pinv (64 batches = both chunks)
        k_pinv_init<<<64, 256, 0, stream>>>(attn2f, z16A);
        u16* zc16 = z16A; u16* zn16 = z16B;
        for (int it = 0; it < 6; ++it) {
            k_bgemm_b16<<<dim3(64, 4, 4), 256, 0, stream>>>(a2b, zc16, xz16, nullptr, 0.f, 1.f);
            k_bgemm_b16<<<dim3(64, 4, 4), 256, 0, stream>>>(xz16, xz16, p116, nullptr, 7.f, -1.f);
            k_bgemm_b16<<<dim3(64, 4, 4), 256, 0, stream>>>(xz16, p116, p216, nullptr, 15.f, -1.f);
            if (it < 5) {
                k_bgemm_b16<<<dim3(64, 4, 4), 256, 0, stream>>>(zc16, p216, zn16, nullptr, 3.25f, -0.25f);
                u16* tmp = zc16; zc16 = zn16; zn16 = tmp;
            } else {
                k_bgemm_b16<<<dim3(64, 4, 4), 256, 0, stream>>>(zc16, p216, nullptr, zF2, 3.25f, -0.25f);
            }
        }
        k_bgemm<<<dim3(64, 4, 1), 256, 0, stream>>>(zF2, out3, nullptr, w216, 64, 0.f, 1.f);
        // phase B: per chunk attn1 + proj
        for (int c = 0; c < NCHUNK; ++c) {
            int b0 = c * CH;
            k_attn1res<<<dim3(32, 96), 256, 0, stream>>>(q16 + c * QVOFF, k_l16 + c * LOFF,
                                                         w216 + c * LOFF, v16 + c * QVOFF,
                                                         res_w, res_b, at16);
            k_gemm<3><<<dim3(4, 192), 256, 0, stream>>>(nullptr, at16, outt, out_b, CH * NTOK, b0,
                                                        h, nullptr, nullptr, nullptr);
        }
        if (l == 0) {
            k_tr_fwd<<<dim3(96, 8, BB), 256, 0, stream>>>(h, ft);
            k_ppeg_t<<<BB * 512, 256, 0, stream>>>(ft, w7, b7, w5, b5, w3, b3);
            k_tr_bwd<<<dim3(96, 8, BB), 256, 0, stream>>>(ft, h);
        }
    }

    k_bag<<<BB, 256, 0, stream>>>(h, lnf_g, lnf_b, bag);
    k_mlp<<<1, 64, 0, stream>>>(bag, fc2w, fc2b, out);
    k_xcat<<<MAXNN, 256, 0, stream>>>(bag, reh, xn);
    k_sim_topk<<<MAXNN, 256, 0, stream>>>(xn, idxb, wgt, dinv);
    k_hh1<<<MAXNN, 256, 0, stream>>>(bag, gw1, hh1);
    k_g1<<<MAXNN, 256, 0, stream>>>(hh1, idxb, wgt, dinv, gb1, gbuf);
    k_hh2<<<MAXNN, 256, 0, stream>>>(gbuf, gw2, hh2);
    k_gout<<<1, 64, 0, stream>>>(hh2, idxb, wgt, dinv, gb2, out);
}

// Round 24
// 2551.174 us; speedup vs baseline: 1.0023x; 1.0023x over previous
//
#include <hip/hip_runtime.h>
#include <math.h>

#define DD 512
#define HEADS 8
#define DHD 64
#define MM 256
#define BB 8
#define CH 4
#define NCHUNK 2
#define NINST 6000
#define SIDE 78
#define PSIDE 84
#define NSQ 6084
#define NTOK 6085
#define PADF 59
#define NPAD 6144
#define LMM 24
#define RESK 33
#define MAXNN 520
#define KNN 12

typedef unsigned short u16;
typedef __attribute__((ext_vector_type(8))) short short8;
typedef __attribute__((ext_vector_type(4))) float f32x4;

__device__ __forceinline__ u16 f2bf(float f) {
    unsigned u = __float_as_uint(f);
    u += 0x7FFF + ((u >> 16) & 1);
    return (u16)(u >> 16);
}
__device__ __forceinline__ float bf2f(u16 v) {
    return __uint_as_float(((unsigned)v) << 16);
}

// async global->LDS, 16B per lane, wave-uniform LDS base
#define GLD_LDS16(src, dst) __builtin_amdgcn_global_load_lds( \
    (const __attribute__((address_space(1))) void*)(src),     \
    (__attribute__((address_space(3))) void*)(dst), 16, 0, 0)

// ---------------- reduction helpers (blockDim == 256 only) ----------------
__device__ __forceinline__ float blockReduceSum(float v, float* red) {
    int t = threadIdx.x;
    red[t] = v; __syncthreads();
    #pragma unroll
    for (int s = 128; s > 0; s >>= 1) { if (t < s) red[t] += red[t + s]; __syncthreads(); }
    float r = red[0]; __syncthreads();
    return r;
}
__device__ __forceinline__ float blockReduceMax(float v, float* red) {
    int t = threadIdx.x;
    red[t] = v; __syncthreads();
    #pragma unroll
    for (int s = 128; s > 0; s >>= 1) { if (t < s) red[t] = fmaxf(red[t], red[t + s]); __syncthreads(); }
    float r = red[0]; __syncthreads();
    return r;
}

// ---------------- diagnostic ----------------
__global__ void k_diag(float* __restrict__ out, float v) {
    int t = threadIdx.x;
    if (t < 32) out[t] = v;
}

// ---------------- weight transpose+convert: W[k][N] f32 -> Wt[n][512] bf16 ----------------
__global__ __launch_bounds__(256) void k_wconv(const float* __restrict__ W, int N, u16* __restrict__ Wt)
{
    __shared__ float tile[64][68];
    int n0 = blockIdx.x * 64, k0 = blockIdx.y * 64;
    int t = threadIdx.x;
    #pragma unroll
    for (int i = 0; i < 4; ++i) {
        int kr = (t >> 4) + i * 16, nc = (t & 15) * 4;
        *(float4*)&tile[kr][nc] = *(const float4*)&W[(size_t)(k0 + kr) * N + n0 + nc];
    }
    __syncthreads();
    int nr = t >> 2, kc = (t & 3) * 16;
    __align__(16) u16 tmp[16];
    #pragma unroll
    for (int j = 0; j < 16; ++j) tmp[j] = f2bf(tile[kc + j][nr]);
    *(uint4*)&Wt[(size_t)(n0 + nr) * 512 + k0 + kc]     = *(uint4*)&tmp[0];
    *(uint4*)&Wt[(size_t)(n0 + nr) * 512 + k0 + kc + 8] = *(uint4*)&tmp[8];
}

// ---------------- per-row LN stats ----------------
__global__ __launch_bounds__(256) void k_lnstat(const float* __restrict__ h, float* __restrict__ st) {
    __shared__ float red[256];
    int row = blockIdx.x;
    int t = threadIdx.x;
    const float* src = h + (size_t)row * 512;
    float x0 = src[t], x1 = src[t + 256];
    float mean = blockReduceSum(x0 + x1, red) * (1.f / 512.f);
    float d0 = x0 - mean, d1 = x1 - mean;
    float var = blockReduceSum(d0 * d0 + d1 * d1, red) * (1.f / 512.f);
    if (t == 0) { st[(size_t)row * 2] = mean; st[(size_t)row * 2 + 1] = 1.f / sqrtf(var + 1e-5f); }
}

// ---------------- LN'd + front-padded activations as bf16 (chunk-local) ----------------
__global__ __launch_bounds__(256) void k_lnbf(const float* __restrict__ h,
    const float* __restrict__ lnstat, const float* __restrict__ g,
    const float* __restrict__ be, int b0, u16* __restrict__ xp)
{
    int rowc = blockIdx.x;
    int b2 = rowc / NPAD, n2 = rowc - b2 * NPAD;
    int t = threadIdx.x;
    u16* dst = xp + (size_t)rowc * 512;
    int c = t * 2;
    if (n2 < PADF) { *(unsigned*)&dst[c] = 0u; return; }
    size_t ridx = (size_t)(b0 + b2) * NTOK + (n2 - PADF);
    const float* src = h + ridx * 512;
    float mu = lnstat[ridx * 2], rs = lnstat[ridx * 2 + 1];
    float v0 = (src[c] - mu) * rs * g[c] + be[c];
    float v1 = (src[c + 1] - mu) * rs * g[c + 1] + be[c + 1];
    u16 p[2] = { f2bf(v0), f2bf(v1) };
    *(unsigned*)&dst[c] = *(unsigned*)p;
}

// ---------------- MFMA bf16 GEMM, K=512, tile 128x128, BK=32; XCD swizzle ----------------
template<int MODE>
__global__ __launch_bounds__(256) void k_gemm(
    const float* __restrict__ A, const u16* __restrict__ A16,
    const u16* __restrict__ Wt, const float* __restrict__ bias,
    int rows, int b0,
    float* __restrict__ hbuf, u16* __restrict__ qb, u16* __restrict__ kb,
    u16* __restrict__ vb)
{
    __shared__ __align__(16) u16 As[128][32];
    __shared__ __align__(16) u16 Bs[128][32];
    int t = threadIdx.x;
    int nwg = gridDim.x * gridDim.y;
    int hid = blockIdx.y * gridDim.x + blockIdx.x;
    int per = nwg >> 3;
    int logical = (hid & 7) * per + (hid >> 3);
    int cx = logical % gridDim.x;
    int ry = logical / gridDim.x;
    int r0 = ry * 128, c0 = cx * 128;
    int w = t >> 6, l = t & 63, lr = l & 15, lg = l >> 4;

    int ch0  = w * 2;
    int crow0 = ch0 * 16 + (l >> 2);
    int ccol  = (l & 3) * 8;

    const u16* bsrc0 = Wt + (size_t)(c0 + crow0) * 512 + ccol;
    const u16* bsrc1 = bsrc0 + (size_t)16 * 512;

    const u16* asrc0 = nullptr; const u16* asrc1 = nullptr;
    if (MODE == 2) {
        asrc0 = A16 + (size_t)(r0 + crow0) * 512 + ccol;
        asrc1 = asrc0 + (size_t)16 * 512;
    } else if (MODE == 3) {
        int gr0 = r0 + crow0;
        int b20 = gr0 / NTOK, r20 = gr0 - b20 * NTOK;
        asrc0 = A16 + ((size_t)b20 * NPAD + r20 + PADF) * 512 + ccol;
        int gr1 = gr0 + 16;
        int b21 = gr1 / NTOK, r21 = gr1 - b21 * NTOK;
        asrc1 = A16 + ((size_t)b21 * NPAD + r21 + PADF) * 512 + ccol;
    }

    int srow = t >> 1, sks = (t & 1) * 16;
    int grow = r0 + srow;
    bool rowok = grow < rows;

    f32x4 acc[2][8];
    #pragma unroll
    for (int i = 0; i < 2; ++i)
        #pragma unroll
        for (int j = 0; j < 8; ++j) acc[i][j] = (f32x4){0.f, 0.f, 0.f, 0.f};

    for (int k0 = 0; k0 < 512; k0 += 32) {
        if (MODE == 1) {
            if (rowok) {
                __align__(16) u16 tmp[16];
                const float* src = A + (size_t)grow * 512 + k0 + sks;
                #pragma unroll
                for (int i = 0; i < 4; ++i) {
                    float4 v4 = *(const float4*)(src + i * 4);
                    tmp[i*4+0] = f2bf(v4.x); tmp[i*4+1] = f2bf(v4.y);
                    tmp[i*4+2] = f2bf(v4.z); tmp[i*4+3] = f2bf(v4.w);
                }
                *(uint4*)&As[srow][sks]     = *(uint4*)&tmp[0];
                *(uint4*)&As[srow][sks + 8] = *(uint4*)&tmp[8];
            } else {
                *(uint4*)&As[srow][sks]     = make_uint4(0, 0, 0, 0);
                *(uint4*)&As[srow][sks + 8] = make_uint4(0, 0, 0, 0);
            }
        } else {
            GLD_LDS16(asrc0 + k0, &As[ch0 * 16][0]);
            GLD_LDS16(asrc1 + k0, &As[ch0 * 16 + 16][0]);
        }
        GLD_LDS16(bsrc0 + k0, &Bs[ch0 * 16][0]);
        GLD_LDS16(bsrc1 + k0, &Bs[ch0 * 16 + 16][0]);
        __syncthreads();
        short8 a0 = *(const short8*)&As[w * 32 + lr][lg * 8];
        short8 a1 = *(const short8*)&As[w * 32 + 16 + lr][lg * 8];
        #pragma unroll
        for (int nf = 0; nf < 8; ++nf) {
            short8 bf = *(const short8*)&Bs[nf * 16 + lr][lg * 8];
            acc[0][nf] = __builtin_amdgcn_mfma_f32_16x16x32_bf16(a0, bf, acc[0][nf], 0, 0, 0);
            acc[1][nf] = __builtin_amdgcn_mfma_f32_16x16x32_bf16(a1, bf, acc[1][nf], 0, 0, 0);
        }
        __syncthreads();
    }
    #pragma unroll
    for (int mf = 0; mf < 2; ++mf) {
        #pragma unroll
        for (int r = 0; r < 4; ++r) {
            int row = r0 + w * 32 + mf * 16 + lg * 4 + r;
            if (row >= rows) continue;
            int b2, r2;
            if (MODE == 1)      { b2 = row / NINST; r2 = row - b2 * NINST; }
            else if (MODE == 2) { b2 = row / NPAD;  r2 = row - b2 * NPAD; }
            else                { b2 = row / NTOK;  r2 = row - b2 * NTOK; }
            #pragma unroll
            for (int nf = 0; nf < 8; ++nf) {
                int col = c0 + nf * 16 + lr;
                float val = acc[mf][nf][r];
                if (MODE == 1) {
                    val += bias[col];
                    val = fmaxf(val, 0.f);
                    hbuf[((size_t)b2 * NTOK + 1 + r2) * 512 + col] = val;
                } else if (MODE == 2) {
                    int which = col >> 9, head = (col >> 6) & 7, dh = col & 63;
                    u16* dst = which == 0 ? qb : (which == 1 ? kb : vb);
                    if (which == 0) val *= 0.125f;
                    dst[(((size_t)b2 * HEADS + head) * NPAD + r2) * 64 + dh] = f2bf(val);
                } else {
                    size_t o = ((size_t)(b0 + b2) * NTOK + r2) * 512 + col;
                    hbuf[o] += val + bias[col];
                }
            }
        }
    }
}

// ---------------- batched 256xNcols f32 GEMM (K=256), optional bf16 out ----------------
__global__ __launch_bounds__(256) void k_bgemm(
    const float* __restrict__ A, const float* __restrict__ B,
    float* __restrict__ C, u16* __restrict__ C16, int ncols, float coefA, float coefAB)
{
    __shared__ float As[16][68];
    __shared__ float Bs[16][68];
    int t = threadIdx.x;
    int bat = blockIdx.x, rt = blockIdx.y, ct = blockIdx.z;
    const float* Ab = A + (size_t)bat * 65536;
    const float* Bb = B + (size_t)bat * 256 * ncols;
    int r0 = rt * 64, c0 = ct * 64;
    int tr = t >> 4, tc = t & 15, lr = t >> 2, lk4 = (t & 3) << 2;
    int wkk = t >> 4, wcc = (t & 15) << 2;
    float acc[4][4] = {{0.f}};
    for (int k0 = 0; k0 < 256; k0 += 16) {
        float4 av = *(const float4*)(Ab + (size_t)(r0 + lr) * 256 + k0 + lk4);
        As[lk4 + 0][lr] = av.x;
        As[lk4 + 1][lr] = av.y;
        As[lk4 + 2][lr] = av.z;
        As[lk4 + 3][lr] = av.w;
        *(float4*)&Bs[wkk][wcc] = *(const float4*)(Bb + (size_t)(k0 + wkk) * ncols + c0 + wcc);
        __syncthreads();
        #pragma unroll
        for (int kk = 0; kk < 16; ++kk) {
            float a[4], b4[4];
            *(float4*)a  = *(float4*)&As[kk][tr << 2];
            *(float4*)b4 = *(float4*)&Bs[kk][tc << 2];
            #pragma unroll
            for (int i2 = 0; i2 < 4; ++i2)
                #pragma unroll
                for (int j2 = 0; j2 < 4; ++j2)
                    acc[i2][j2] += a[i2] * b4[j2];
        }
        __syncthreads();
    }
    #pragma unroll
    for (int i2 = 0; i2 < 4; ++i2) {
        int row = r0 + (tr << 2) + i2;
        #pragma unroll
        for (int j2 = 0; j2 < 4; ++j2) {
            int col = c0 + (tc << 2) + j2;
            float val = coefAB * acc[i2][j2];
            if (coefA != 0.f) val += coefA * Ab[(size_t)row * 256 + col];
            size_t o = (size_t)bat * 256 * ncols + (size_t)row * ncols + col;
            if (C16) C16[o] = f2bf(val);
            else     C[o] = val;
        }
    }
}

// ---------------- batched MFMA GEMM, bf16 in / bf16-or-f32 out (K=256, N=256) ----------------
__global__ __launch_bounds__(256) void k_bgemm_b16(
    const u16* __restrict__ A, const u16* __restrict__ B,
    u16* __restrict__ C, float* __restrict__ Cf, float coefA, float coefAB)
{
    __shared__ __align__(16) u16 As[64][40];
    __shared__ __align__(16) u16 Bs[64][40];
    int t = threadIdx.x;
    int bat = blockIdx.x, rt = blockIdx.y, ct = blockIdx.z;
    const u16* Ab = A + (size_t)bat * 65536;
    const u16* Bb = B + (size_t)bat * 65536;
    int r0 = rt * 64, c0 = ct * 64;
    int w = t >> 6, l = t & 63, lr = l & 15, lg = l >> 4;
    int am = t >> 2, ak = (t & 3) * 8;
    int bn = t & 63, bk0 = t >> 6 << 3;
    f32x4 acc[4];
    #pragma unroll
    for (int j = 0; j < 4; ++j) acc[j] = (f32x4){0.f, 0.f, 0.f, 0.f};
    for (int k0 = 0; k0 < 256; k0 += 32) {
        *(uint4*)&As[am][ak] = *(const uint4*)&Ab[(size_t)(r0 + am) * 256 + k0 + ak];
        __align__(16) u16 tb[8];
        #pragma unroll
        for (int i = 0; i < 8; ++i)
            tb[i] = Bb[(size_t)(k0 + bk0 + i) * 256 + c0 + bn];
        *(uint4*)&Bs[bn][bk0] = *(uint4*)&tb[0];
        __syncthreads();
        short8 a = *(const short8*)&As[w * 16 + lr][lg * 8];
        #pragma unroll
        for (int nf = 0; nf < 4; ++nf) {
            short8 bf = *(const short8*)&Bs[nf * 16 + lr][lg * 8];
            acc[nf] = __builtin_amdgcn_mfma_f32_16x16x32_bf16(a, bf, acc[nf], 0, 0, 0);
        }
        __syncthreads();
    }
    #pragma unroll
    for (int r = 0; r < 4; ++r) {
        int row = r0 + w * 16 + lg * 4 + r;
        #pragma unroll
        for (int nf = 0; nf < 4; ++nf) {
            int col = c0 + nf * 16 + lr;
            float val = coefAB * acc[nf][r];
            if (coefA != 0.f) val += coefA * bf2f(Ab[(size_t)row * 256 + col]);
            if (Cf) Cf[(size_t)bat * 65536 + (size_t)row * 256 + col] = val;
            else    C[(size_t)bat * 65536 + (size_t)row * 256 + col] = f2bf(val);
        }
    }
}

// ---------------- wrap rows + cls token ----------------
__global__ void k_fixup(float* __restrict__ h, const float* __restrict__ cls)
{
    int b = blockIdx.x, r = blockIdx.y, t = threadIdx.x;
    float* dst; const float* src;
    if (r < 84) {
        dst = h + ((size_t)b * NTOK + 6001 + r) * 512;
        src = h + ((size_t)b * NTOK + 1 + r) * 512;
    } else {
        dst = h + (size_t)b * NTOK * 512;
        src = cls;
    }
    dst[t] = src[t]; dst[t + 256] = src[t + 256];
}

// ---------------- landmarks (bf16 in, f32 + bf16 out) ----------------
__global__ void k_landmark(const u16* __restrict__ q, const u16* __restrict__ k,
                           float* __restrict__ q_l, float* __restrict__ k_l,
                           u16* __restrict__ k_l16)
{
    int bhm = blockIdx.x;
    int d = threadIdx.x;
    int bh = bhm >> 8, m = bhm & 255;
    const u16* qs = q + ((size_t)bh * NPAD + m * LMM) * 64 + d;
    const u16* ks = k + ((size_t)bh * NPAD + m * LMM) * 64 + d;
    float sq = 0.f, sk = 0.f;
    #pragma unroll
    for (int j = 0; j < LMM; ++j) { sq += bf2f(qs[(size_t)j * 64]); sk += bf2f(ks[(size_t)j * 64]); }
    float kv = sk * (1.f / 24.f);
    q_l[(size_t)bhm * 64 + d] = sq * (1.f / 24.f);
    k_l[(size_t)bhm * 64 + d] = kv;
    k_l16[(size_t)bhm * 64 + d] = f2bf(kv);
}

// ---------------- attn2 = softmax(q_l @ k_l^T), f32 + bf16 outputs ----------------
__global__ __launch_bounds__(256) void k_attn2(const float* __restrict__ q_l,
    const float* __restrict__ k_l, float* __restrict__ attn2, u16* __restrict__ a2b)
{
    __shared__ float ql[64];
    __shared__ float red[256];
    int bh = blockIdx.x >> 8, i = blockIdx.x & 255;
    int t = threadIdx.x;
    if (t < 64) ql[t] = q_l[((size_t)(bh * 256 + i)) * 64 + t];
    __syncthreads();
    const float4* kr = (const float4*)(k_l + ((size_t)bh * 256 + t) * 64);
    float s = 0.f;
    #pragma unroll
    for (int d4 = 0; d4 < 16; ++d4) {
        float4 kv = kr[d4];
        s += ql[d4 * 4] * kv.x + ql[d4 * 4 + 1] * kv.y + ql[d4 * 4 + 2] * kv.z + ql[d4 * 4 + 3] * kv.w;
    }
    float mx = blockReduceMax(s, red);
    float e = expf(s - mx);
    float S = blockReduceSum(e, red);
    float p = e / S;
    size_t o = ((size_t)(bh * 256 + i)) * 256 + t;
    attn2[o] = p;
    a2b[o] = f2bf(p);
}

// ---------------- pinv init -> bf16 ----------------
__global__ __launch_bounds__(256) void k_pinv_init(const float* __restrict__ x, u16* __restrict__ z16)
{
    __shared__ float red[256];
    int bh = blockIdx.x, t = threadIdx.x;
    const float* xb = x + (size_t)bh * 65536;
    float rs = 0.f;
    for (int j = 0; j < 256; ++j) rs += xb[t * 256 + j];
    float colv = blockReduceMax(rs, red);
    float cs = 0.f;
    for (int i2 = 0; i2 < 256; ++i2) cs += xb[i2 * 256 + t];
    float rowv = blockReduceMax(cs, red);
    float scale = 1.f / (colv * rowv);
    u16* zb = z16 + (size_t)bh * 65536;
    for (int i2 = 0; i2 < 256; ++i2)
        zb[(size_t)i2 * 256 + t] = f2bf(xb[(size_t)t * 256 + i2] * scale);
}

// ---------------- attn3 @ v : flash MFMA-bf16 partial kernel (bf16 K/V) ----------------
__global__ __launch_bounds__(256) void k_attn3_part(
    const float* __restrict__ q_l, const u16* __restrict__ kbuf,
    const u16* __restrict__ vbuf, float* __restrict__ pv, float* __restrict__ pstat)
{
    __shared__ __align__(16) u16 Qb[64][72];
    __shared__ __align__(16) u16 Kb[64][72];
    __shared__ __align__(16) u16 Pb[64][72];
    int bh = blockIdx.x, mb = blockIdx.y, ns = blockIdx.z;
    int t = threadIdx.x, w = t >> 6, l = t & 63, lr = l & 15, lg = l >> 4;
    {
        int srow = t >> 2, sd = (t & 3) * 16;
        const float* src = q_l + ((size_t)bh * 256 + mb * 64 + srow) * 64 + sd;
        __align__(16) u16 tmp[16];
        #pragma unroll
        for (int i = 0; i < 16; ++i) tmp[i] = f2bf(src[i]);
        *(uint4*)&Qb[srow][sd]     = *(uint4*)&tmp[0];
        *(uint4*)&Qb[srow][sd + 8] = *(uint4*)&tmp[8];
    }
    f32x4 acc[4];
    #pragma unroll
    for (int j = 0; j < 4; ++j) acc[j] = (f32x4){0.f, 0.f, 0.f, 0.f};
    float m_run[4], s_run[4];
    #pragma unroll
    for (int i = 0; i < 4; ++i) { m_run[i] = -INFINITY; s_run[i] = 0.f; }
    const int n00 = ns * 768;
    for (int tile = 0; tile < 12; ++tile) {
        int nb = n00 + tile * 64;
        __syncthreads();
        {
            int srow = t >> 2, sd = (t & 3) * 16;
            const u16* src = kbuf + ((size_t)bh * NPAD + nb + srow) * 64 + sd;
            *(uint4*)&Kb[srow][sd]     = *(const uint4*)&src[0];
            *(uint4*)&Kb[srow][sd + 8] = *(const uint4*)&src[8];
        }
        __syncthreads();
        f32x4 s[4];
        #pragma unroll
        for (int j = 0; j < 4; ++j) s[j] = (f32x4){0.f, 0.f, 0.f, 0.f};
        #pragma unroll
        for (int ks = 0; ks < 64; ks += 32) {
            short8 a = *(const short8*)&Qb[w * 16 + lr][lg * 8 + ks];
            #pragma unroll
            for (int nf = 0; nf < 4; ++nf) {
                short8 bf = *(const short8*)&Kb[nf * 16 + lr][lg * 8 + ks];
                s[nf] = __builtin_amdgcn_mfma_f32_16x16x32_bf16(a, bf, s[nf], 0, 0, 0);
            }
        }
        #pragma unroll
        for (int r = 0; r < 4; ++r) {
            float lm = fmaxf(fmaxf(s[0][r], s[1][r]), fmaxf(s[2][r], s[3][r]));
            #pragma unroll
            for (int off = 1; off < 16; off <<= 1)
                lm = fmaxf(lm, __shfl_xor(lm, off, 16));
            float m_new = fmaxf(m_run[r], lm);
            float scf = expf(m_run[r] - m_new);
            s_run[r] *= scf;
            acc[0][r] *= scf; acc[1][r] *= scf; acc[2][r] *= scf; acc[3][r] *= scf;
            float p0 = expf(s[0][r] - m_new), p1 = expf(s[1][r] - m_new);
            float p2 = expf(s[2][r] - m_new), p3 = expf(s[3][r] - m_new);
            float ls = p0 + p1 + p2 + p3;
            #pragma unroll
            for (int off = 1; off < 16; off <<= 1)
                ls += __shfl_xor(ls, off, 16);
            s_run[r] += ls;
            m_run[r] = m_new;
            int prow = w * 16 + lg * 4 + r;
            Pb[prow][lr]      = f2bf(p0);
            Pb[prow][16 + lr] = f2bf(p1);
            Pb[prow][32 + lr] = f2bf(p2);
            Pb[prow][48 + lr] = f2bf(p3);
        }
        __syncthreads();
        {
            int nl = t & 63, dvb = (t >> 6) * 16;
            const u16* src = vbuf + ((size_t)bh * NPAD + nb + nl) * 64 + dvb;
            __align__(16) u16 tmp[16];
            *(uint4*)&tmp[0] = *(const uint4*)&src[0];
            *(uint4*)&tmp[8] = *(const uint4*)&src[8];
            #pragma unroll
            for (int j = 0; j < 16; ++j) Kb[dvb + j][nl] = tmp[j];
        }
        __syncthreads();
        #pragma unroll
        for (int ks = 0; ks < 64; ks += 32) {
            short8 a = *(const short8*)&Pb[w * 16 + lr][lg * 8 + ks];
            #pragma unroll
            for (int df = 0; df < 4; ++df) {
                short8 bf = *(const short8*)&Kb[df * 16 + lr][lg * 8 + ks];
                acc[df] = __builtin_amdgcn_mfma_f32_16x16x32_bf16(a, bf, acc[df], 0, 0, 0);
            }
        }
    }
    #pragma unroll
    for (int r = 0; r < 4; ++r) {
        int mloc = w * 16 + lg * 4 + r;
        size_t row = (size_t)bh * 256 + mb * 64 + mloc;
        float* dst = pv + (row * 8 + ns) * 64;
        dst[lr]      = acc[0][r];
        dst[16 + lr] = acc[1][r];
        dst[32 + lr] = acc[2][r];
        dst[48 + lr] = acc[3][r];
        if (lr == 0) { pstat[row * 16 + ns * 2] = m_run[r]; pstat[row * 16 + ns * 2 + 1] = s_run[r]; }
    }
}

// combine 8 slices -> out3
__global__ __launch_bounds__(256) void k_attn3_comb(
    const float* __restrict__ pv, const float* __restrict__ pstat, float* __restrict__ out3)
{
    size_t row = (size_t)blockIdx.x * 4 + (threadIdx.x >> 6);
    int d = threadIdx.x & 63;
    float M = -INFINITY;
    #pragma unroll
    for (int s = 0; s < 8; ++s) M = fmaxf(M, pstat[row * 16 + s * 2]);
    float num = 0.f, den = 0.f;
    #pragma unroll
    for (int s = 0; s < 8; ++s) {
        float w = expf(pstat[row * 16 + s * 2] - M);
        den += w * pstat[row * 16 + s * 2 + 1];
        num += w * pv[(row * 8 + s) * 64 + d];
    }
    out3[row * 64 + d] = num / den;
}

// ---------------- attn1 softmax @ w2 + res conv + res_b; bf16 bufv, 31KB LDS ----------------
__global__ __launch_bounds__(256) void k_attn1res(
    const u16* __restrict__ qbuf, const u16* __restrict__ k_l16,
    const u16* __restrict__ w216, const u16* __restrict__ vbuf,
    const float* __restrict__ res_w, const float* __restrict__ res_b,
    u16* __restrict__ outb16)
{
    __shared__ __align__(16) char smem[31232];
    u16 (*Qb)[72]   = (u16(*)[72])smem;
    u16 (*Kb)[72]   = (u16(*)[72])(smem + 9216);
    u16 (*Pb)[72]   = (u16(*)[72])(smem + 18432);
    float (*osm)[68] = (float(*)[68])smem;
    u16 (*bufv)[72]  = (u16(*)[72])(smem + 17408);
    __shared__ float wconv[RESK];
    int bh = blockIdx.x, nb = blockIdx.y, hh = bh & 7;
    int b2 = bh >> 3;
    int t = threadIdx.x, w = t >> 6, l = t & 63, lr = l & 15, lg = l >> 4;
    int tr = t >> 4, tc = t & 15;
    int n0 = nb * 64;
    if (t < RESK) wconv[t] = res_w[hh * RESK + t];
    {
        int srow = t >> 2, sd = (t & 3) * 16;
        const u16* src = qbuf + ((size_t)bh * NPAD + n0 + srow) * 64 + sd;
        *(uint4*)&Qb[srow][sd]     = *(const uint4*)&src[0];
        *(uint4*)&Qb[srow][sd + 8] = *(const uint4*)&src[8];
    }
    f32x4 acc[4];
    #pragma unroll
    for (int j = 0; j < 4; ++j) acc[j] = (f32x4){0.f, 0.f, 0.f, 0.f};
    float m_run[4], s_run[4];
    #pragma unroll
    for (int i = 0; i < 4; ++i) { m_run[i] = -INFINITY; s_run[i] = 0.f; }
    for (int mt = 0; mt < 4; ++mt) {
        __syncthreads();
        {
            int srow = t >> 2, sd = (t & 3) * 16;
            const u16* src = k_l16 + ((size_t)bh * 256 + mt * 64 + srow) * 64 + sd;
            *(uint4*)&Kb[srow][sd]     = *(const uint4*)&src[0];
            *(uint4*)&Kb[srow][sd + 8] = *(const uint4*)&src[8];
        }
        __syncthreads();
        f32x4 s[4];
        #pragma unroll
        for (int j = 0; j < 4; ++j) s[j] = (f32x4){0.f, 0.f, 0.f, 0.f};
        #pragma unroll
        for (int ks = 0; ks < 64; ks += 32) {
            short8 a = *(const short8*)&Qb[w * 16 + lr][lg * 8 + ks];
            #pragma unroll
            for (int nf = 0; nf < 4; ++nf) {
                short8 bf = *(const short8*)&Kb[nf * 16 + lr][lg * 8 + ks];
                s[nf] = __builtin_amdgcn_mfma_f32_16x16x32_bf16(a, bf, s[nf], 0, 0, 0);
            }
        }
        #pragma unroll
        for (int r = 0; r < 4; ++r) {
            float lm = fmaxf(fmaxf(s[0][r], s[1][r]), fmaxf(s[2][r], s[3][r]));
            #pragma unroll
            for (int off = 1; off < 16; off <<= 1)
                lm = fmaxf(lm, __shfl_xor(lm, off, 16));
            float m_new = fmaxf(m_run[r], lm);
            float scf = expf(m_run[r] - m_new);
            s_run[r] *= scf;
            acc[0][r] *= scf; acc[1][r] *= scf; acc[2][r] *= scf; acc[3][r] *= scf;
            float p0 = expf(s[0][r] - m_new), p1 = expf(s[1][r] - m_new);
            float p2 = expf(s[2][r] - m_new), p3 = expf(s[3][r] - m_new);
            float ls = p0 + p1 + p2 + p3;
            #pragma unroll
            for (int off = 1; off < 16; off <<= 1)
                ls += __shfl_xor(ls, off, 16);
            s_run[r] += ls;
            m_run[r] = m_new;
            int prow = w * 16 + lg * 4 + r;
            Pb[prow][lr]      = f2bf(p0);
            Pb[prow][16 + lr] = f2bf(p1);
            Pb[prow][32 + lr] = f2bf(p2);
            Pb[prow][48 + lr] = f2bf(p3);
        }
        __syncthreads();
        {
            int nl = t & 63, dvb = (t >> 6) * 16;
            const u16* src = w216 + ((size_t)bh * 256 + mt * 64 + nl) * 64 + dvb;
            __align__(16) u16 tmp[16];
            *(uint4*)&tmp[0] = *(const uint4*)&src[0];
            *(uint4*)&tmp[8] = *(const uint4*)&src[8];
            #pragma unroll
            for (int j = 0; j < 16; ++j) Kb[dvb + j][nl] = tmp[j];
        }
        __syncthreads();
        #pragma unroll
        for (int ks = 0; ks < 64; ks += 32) {
            short8 a = *(const short8*)&Pb[w * 16 + lr][lg * 8 + ks];
            #pragma unroll
            for (int df = 0; df < 4; ++df) {
                short8 bf = *(const short8*)&Kb[df * 16 + lr][lg * 8 + ks];
                acc[df] = __builtin_amdgcn_mfma_f32_16x16x32_bf16(a, bf, acc[df], 0, 0, 0);
            }
        }
    }
    __syncthreads();
    #pragma unroll
    for (int r = 0; r < 4; ++r) {
        float inv = 1.f / s_run[r];
        int m = w * 16 + lg * 4 + r;
        osm[m][lr]      = acc[0][r] * inv;
        osm[m][16 + lr] = acc[1][r] * inv;
        osm[m][32 + lr] = acc[2][r] * inv;
        osm[m][48 + lr] = acc[3][r] * inv;
    }
    for (int idx = t; idx < 96 * 8; idx += 256) {
        int rowl = idx >> 3, d8 = (idx & 7) * 8;
        int gn = n0 - 16 + rowl;
        uint4 v4 = make_uint4(0u, 0u, 0u, 0u);
        if (gn >= 0 && gn < NPAD)
            v4 = *(const uint4*)(vbuf + ((size_t)bh * NPAD + gn) * 64 + d8);
        *(uint4*)&bufv[rowl][d8] = v4;
    }
    __syncthreads();
    float rb = res_b[hh];
    #pragma unroll
    for (int i = 0; i < 4; ++i) {
        int rl = tr * 4 + i;
        int n = n0 + rl;
        if (n < PADF) continue;
        float4 oo = *(float4*)&osm[rl][tc * 4];
        float o0 = oo.x, o1 = oo.y, o2 = oo.z, o3 = oo.w;
        #pragma unroll
        for (int jj = 0; jj < RESK; ++jj) {
            float wj = wconv[jj];
            u16 q4[4];
            *(uint2*)q4 = *(const uint2*)&bufv[rl + jj][tc * 4];
            o0 += wj * bf2f(q4[0]); o1 += wj * bf2f(q4[1]);
            o2 += wj * bf2f(q4[2]); o3 += wj * bf2f(q4[3]);
        }
        u16 ob[4] = { f2bf(o0 + rb), f2bf(o1 + rb), f2bf(o2 + rb), f2bf(o3 + rb) };
        u16* dst = outb16 + ((size_t)b2 * NPAD + n) * 512 + hh * 64 + tc * 4;
        *(uint2*)dst = *(uint2*)ob;
    }
}

// ---------------- PPEG via transpose ----------------
__global__ __launch_bounds__(256) void k_tr_fwd(const float* __restrict__ h, float* __restrict__ ft)
{
    __shared__ float tile[64][68];
    int tt = blockIdx.x, ct8 = blockIdx.y, b = blockIdx.z;
    int t = threadIdx.x;
    int p0 = tt * 64, c0 = ct8 * 64;
    #pragma unroll
    for (int i = 0; i < 4; ++i) {
        int plr = (t >> 4) + i * 16;
        int cl = (t & 15) * 4;
        int p = p0 + plr;
        if (p < NSQ) {
            float4 v = *(const float4*)(h + ((size_t)b * NTOK + 1 + p) * 512 + c0 + cl);
            *(float4*)&tile[plr][cl] = v;
        }
    }
    __syncthreads();
    #pragma unroll
    for (int i = 0; i < 4; ++i) {
        int cl = (t >> 4) + i * 16;
        int plr = (t & 15) * 4;
        if (p0 + plr + 3 < NSQ) {
            float4 v = make_float4(tile[plr][cl], tile[plr + 1][cl], tile[plr + 2][cl], tile[plr + 3][cl]);
            *(float4*)(ft + ((size_t)b * 512 + c0 + cl) * NSQ + p0 + plr) = v;
        }
    }
}

__global__ __launch_bounds__(256) void k_tr_bwd(const float* __restrict__ ft, float* __restrict__ h)
{
    __shared__ float tile[64][68];
    int tt = blockIdx.x, ct8 = blockIdx.y, b = blockIdx.z;
    int t = threadIdx.x;
    int p0 = tt * 64, c0 = ct8 * 64;
    #pragma unroll
    for (int i = 0; i < 4; ++i) {
        int cl = (t >> 4) + i * 16;
        int plr = (t & 15) * 4;
        if (p0 + plr + 3 < NSQ) {
            float4 v = *(const float4*)(ft + ((size_t)b * 512 + c0 + cl) * NSQ + p0 + plr);
            tile[plr][cl] = v.x; tile[plr + 1][cl] = v.y;
            tile[plr + 2][cl] = v.z; tile[plr + 3][cl] = v.w;
        }
    }
    __syncthreads();
    #pragma unroll
    for (int i = 0; i < 4; ++i) {
        int plr = (t >> 4) + i * 16;
        int cl = (t & 15) * 4;
        int p = p0 + plr;
        if (p < NSQ) {
            float4 v = *(float4*)&tile[plr][cl];
            *(float4*)(h + ((size_t)b * NTOK + 1 + p) * 512 + c0 + cl) = v;
        }
    }
}

// per (b, channel) plane: combined 7x7 weights, register-blocked 4 outputs/thread
__global__ __launch_bounds__(256) void k_ppeg_t(float* __restrict__ ft,
    const float* __restrict__ w7, const float* __restrict__ b7,
    const float* __restrict__ w5, const float* __restrict__ b5,
    const float* __restrict__ w3, const float* __restrict__ b3)
{
    __shared__ __align__(16) float f[PSIDE * PSIDE];
    __shared__ float wt[49];
    int bc = blockIdx.x;
    int b = bc >> 9, c = bc & 511;
    int t = threadIdx.x;
    float* plane = ft + ((size_t)b * 512 + c) * NSQ;
    for (int i = t; i < PSIDE * PSIDE; i += 256) f[i] = 0.f;
    if (t < 49) {
        int dy = t / 7 - 3, dx = t % 7 - 3;
        float v = w7[c * 49 + t];
        if (dy >= -2 && dy <= 2 && dx >= -2 && dx <= 2) v += w5[c * 25 + (dy + 2) * 5 + (dx + 2)];
        if (dy >= -1 && dy <= 1 && dx >= -1 && dx <= 1) v += w3[c * 9 + (dy + 1) * 3 + (dx + 1)];
        wt[t] = v;
    }
    __syncthreads();
    for (int p = t; p < NSQ; p += 256) {
        int r = p / SIDE, s2 = p - r * SIDE;
        f[(r + 3) * PSIDE + s2 + 3] = plane[p];
    }
    __syncthreads();
    float bsum = b7[c] + b5[c] + b3[c];
    for (int st = t; st < SIDE * 20; st += 256) {
        int r = st / 20, s0 = (st - (st / 20) * 20) * 4;
        float a0 = bsum + f[(r + 3) * PSIDE + s0 + 3];
        float a1 = bsum + f[(r + 3) * PSIDE + s0 + 4];
        float a2 = bsum + f[(r + 3) * PSIDE + s0 + 5];
        float a3 = bsum + f[(r + 3) * PSIDE + s0 + 6];
        #pragma unroll
        for (int dyy = 0; dyy < 7; ++dyy) {
            const float* rowp = &f[(r + dyy) * PSIDE + s0];
            float win[12];
            *(float4*)&win[0] = *(const float4*)&rowp[0];
            *(float4*)&win[4] = *(const float4*)&rowp[4];
            *(float4*)&win[8] = *(const float4*)&rowp[8];
            const float* wr = &wt[dyy * 7];
            #pragma unroll
            for (int dxx = 0; dxx < 7; ++dxx) {
                float wj = wr[dxx];
                a0 += win[0 + dxx] * wj;
                a1 += win[1 + dxx] * wj;
                a2 += win[2 + dxx] * wj;
                a3 += win[3 + dxx] * wj;
            }
        }
        int base = r * SIDE + s0;
        plane[base] = a0;
        if (s0 + 1 < SIDE) plane[base + 1] = a1;
        if (s0 + 2 < SIDE) plane[base + 2] = a2;
        if (s0 + 3 < SIDE) plane[base + 3] = a3;
    }
}

// ---------------- final LN of cls token ----------------
__global__ __launch_bounds__(256) void k_bag(const float* __restrict__ h,
    const float* __restrict__ g, const float* __restrict__ be, float* __restrict__ bag)
{
    __shared__ float red[256];
    int b = blockIdx.x, t = threadIdx.x;
    const float* src = h + (size_t)b * NTOK * 512;
    float x0 = src[t], x1 = src[t + 256];
    float mean = blockReduceSum(x0 + x1, red) * (1.f / 512.f);
    float d0 = x0 - mean, d1 = x1 - mean;
    float var = blockReduceSum(d0 * d0 + d1 * d1, red) * (1.f / 512.f);
    float rs = 1.f / sqrtf(var + 1e-5f);
    bag[b * 512 + t]       = d0 * rs * g[t] + be[t];
    bag[b * 512 + t + 256] = d1 * rs * g[t + 256] + be[t + 256];
}

__global__ void k_mlp(const float* __restrict__ bag, const float* __restrict__ fc2w,
                      const float* __restrict__ fc2b, float* __restrict__ out)
{
    int t = threadIdx.x;
    if (t < 16) {
        int b = t >> 1, c = t & 1;
        float val = fc2b[c];
        for (int k2 = 0; k2 < 512; ++k2) val += bag[b * 512 + k2] * fc2w[k2 * 2 + c];
        out[b * 2 + c] = val;
    }
}

__global__ __launch_bounds__(256) void k_xcat(const float* __restrict__ bag,
    const float* __restrict__ reh, float* __restrict__ xn)
{
    __shared__ float red[256];
    int i = blockIdx.x, t = threadIdx.x;
    const float* src = (i < BB) ? (bag + (size_t)i * 512) : (reh + (size_t)(i - BB) * 512);
    float x0 = src[t], x1 = src[t + 256];
    float nrm = sqrtf(blockReduceSum(x0 * x0 + x1 * x1, red));
    float inv = 1.f / (nrm + 1e-8f);
    xn[(size_t)i * 512 + t]       = x0 * inv;
    xn[(size_t)i * 512 + t + 256] = x1 * inv;
}

// ---------------- sim row + top-12 (4-acc ILP dot + wave-shfl argmax) ----------------
__global__ __launch_bounds__(256) void k_sim_topk(const float* __restrict__ xn,
    int* __restrict__ idxb, float* __restrict__ wgt, float* __restrict__ dinvb)
{
    __shared__ float xi[512];
    __shared__ float s[MAXNN];
    __shared__ float wv[4];
    __shared__ int wi_[4];
    int i = blockIdx.x, t = threadIdx.x;
    xi[t] = xn[(size_t)i * 512 + t];
    xi[t + 256] = xn[(size_t)i * 512 + t + 256];
    __syncthreads();
    for (int j = t; j < MAXNN; j += 256) {
        const float4* xj = (const float4*)(xn + (size_t)j * 512);
        float a0 = 0.f, a1 = 0.f, a2 = 0.f, a3 = 0.f;
        for (int d4 = 0; d4 < 128; d4 += 4) {
            float4 v0 = xj[d4], v1 = xj[d4 + 1], v2 = xj[d4 + 2], v3 = xj[d4 + 3];
            const float* x0 = &xi[d4 * 4];
            a0 += x0[0]  * v0.x + x0[1]  * v0.y + x0[2]  * v0.z + x0[3]  * v0.w;
            a1 += x0[4]  * v1.x + x0[5]  * v1.y + x0[6]  * v1.z + x0[7]  * v1.w;
            a2 += x0[8]  * v2.x + x0[9]  * v2.y + x0[10] * v2.z + x0[11] * v2.w;
            a3 += x0[12] * v3.x + x0[13] * v3.y + x0[14] * v3.z + x0[15] * v3.w;
        }
        float dot = (a0 + a1) + (a2 + a3);
        s[j] = dot - (j == i ? 1e9f : 0.f);
    }
    __syncthreads();
    float degsum = 0.f;
    for (int kk = 0; kk < KNN; ++kk) {
        float bv = -INFINITY; int bi = MAXNN;
        for (int j = t; j < MAXNN; j += 256) {
            float vv = s[j];
            if (vv > bv) { bv = vv; bi = j; }
        }
        // 64-lane wave argmax (smaller index wins ties)
        #pragma unroll
        for (int off = 32; off > 0; off >>= 1) {
            float ov = __shfl_down(bv, off);
            int   oi = __shfl_down(bi, off);
            if (ov > bv || (ov == bv && oi < bi)) { bv = ov; bi = oi; }
        }
        if ((t & 63) == 0) { wv[t >> 6] = bv; wi_[t >> 6] = bi; }
        __syncthreads();
        if (t == 0) {
            bv = wv[0]; bi = wi_[0];
            #pragma unroll
            for (int q = 1; q < 4; ++q)
                if (wv[q] > bv || (wv[q] == bv && wi_[q] < bi)) { bv = wv[q]; bi = wi_[q]; }
            idxb[i * KNN + kk] = bi;
            float ww = fmaxf(bv, 0.f);
            wgt[i * KNN + kk] = ww;
            degsum += ww;
            s[bi] = -INFINITY;
            if (kk == KNN - 1) dinvb[i] = 1.f / sqrtf(1.f + degsum);
        }
        __syncthreads();
    }
}

// ---------------- GCN ----------------
__global__ __launch_bounds__(256) void k_hh1(const float* __restrict__ bag,
    const float* __restrict__ w1, float* __restrict__ hh1)
{
    int i = blockIdx.x, t = threadIdx.x;
    if (i >= BB) { hh1[(size_t)i * 256 + t] = 0.f; return; }
    float acc = 0.f;
    for (int k2 = 0; k2 < 512; ++k2) acc += bag[i * 512 + k2] * w1[(size_t)k2 * 256 + t];
    hh1[(size_t)i * 256 + t] = acc;
}

__global__ __launch_bounds__(256) void k_g1(const float* __restrict__ hh1,
    const int* __restrict__ idxb, const float* __restrict__ wgt,
    const float* __restrict__ dinvb, const float* __restrict__ b1, float* __restrict__ g)
{
    __shared__ float cf[KNN];
    __shared__ int src[KNN];
    int i = blockIdx.x, t = threadIdx.x;
    if (t < KNN) {
        int s2 = idxb[i * KNN + t];
        src[t] = s2;
        cf[t] = wgt[i * KNN + t] * dinvb[s2] * dinvb[i];
    }
    __syncthreads();
    float di = dinvb[i];
    float val = hh1[(size_t)i * 256 + t] * di * di + b1[t];
    #pragma unroll
    for (int e = 0; e < KNN; ++e) val += cf[e] * hh1[(size_t)src[e] * 256 + t];
    g[(size_t)i * 256 + t] = fmaxf(val, 0.f);
}

__global__ __launch_bounds__(256) void k_hh2(const float* __restrict__ g,
    const float* __restrict__ w2g, float* __restrict__ hh2)
{
    __shared__ float red[256];
    int i = blockIdx.x, t = threadIdx.x;
    float gg = g[(size_t)i * 256 + t];
    float s0 = blockReduceSum(gg * w2g[t * 2 + 0], red);
    float s1 = blockReduceSum(gg * w2g[t * 2 + 1], red);
    if (t == 0) { hh2[i * 2 + 0] = s0; hh2[i * 2 + 1] = s1; }
}

__global__ void k_gout(const float* __restrict__ hh2, const int* __restrict__ idxb,
    const float* __restrict__ wgt, const float* __restrict__ dinvb,
    const float* __restrict__ b2, float* __restrict__ out)
{
    int t = threadIdx.x;
    if (t < 16) {
        int i = t >> 1, c = t & 1;
        float di = dinvb[i];
        float val = hh2[i * 2 + c] * di * di + b2[c];
        for (int e = 0; e < KNN; ++e) {
            int s2 = idxb[i * KNN + e];
            val += wgt[i * KNN + e] * dinvb[s2] * di * hh2[s2 * 2 + c];
        }
        out[16 + i * 2 + c] = val;
    }
}

extern "C" void kernel_launch(void* const* d_in, const int* in_sizes, int n_in,
                              void* d_out, int out_size, void* d_ws, size_t ws_size,
                              hipStream_t stream)
{
    (void)in_sizes; (void)n_in; (void)out_size;
    const float* x     = (const float*)d_in[0];
    const float* fc1_w = (const float*)d_in[1];
    const float* fc1_b = (const float*)d_in[2];
    const float* cls   = (const float*)d_in[3];
    const float* lp[2][7];
    for (int l = 0; l < 2; ++l)
        for (int j = 0; j < 7; ++j)
            lp[l][j] = (const float*)d_in[4 + l * 7 + j];
    const float* w7 = (const float*)d_in[18]; const float* b7 = (const float*)d_in[19];
    const float* w5 = (const float*)d_in[20]; const float* b5 = (const float*)d_in[21];
    const float* w3 = (const float*)d_in[22]; const float* b3 = (const float*)d_in[23];
    const float* lnf_g = (const float*)d_in[24]; const float* lnf_b = (const float*)d_in[25];
    const float* fc2w = (const float*)d_in[26]; const float* fc2b = (const float*)d_in[27];
    const float* gw1 = (const float*)d_in[28]; const float* gb1 = (const float*)d_in[29];
    const float* gw2 = (const float*)d_in[30]; const float* gb2 = (const float*)d_in[31];
    const float* reh = (const float*)d_in[32];
    float* out = (float*)d_out;

    // Workspace budget: 92,943,144 floats = 371,772,576 bytes (ws has 376 MiB).
    const size_t REQUIRED = 92943144ull * 4ull;
    if (ws_size < REQUIRED) {
        k_diag<<<1, 32, 0, stream>>>(out, (float)ws_size);
        return;
    }

    float* Wf = (float*)d_ws;
    size_t off = 0;
    auto alloc = [&](size_t n) { float* p = Wf + off; off += n; return p; };
    float* h      = alloc((size_t)BB * NTOK * 512);
    float* lnstat = alloc((size_t)BB * NTOK * 2);
    u16* q16 = (u16*)alloc(12582912);   // BB*NPAD*512 u16 (full batch); ft overlay here
    u16* k16 = (u16*)alloc(6291456);    // CH*NPAD*512 u16 (chunk-local)
    u16* v16 = (u16*)alloc(12582912);   // full batch
    float* q_l  = alloc((size_t)CH * HEADS * 256 * 64);   // chunk-local
    float* k_l  = alloc((size_t)CH * HEADS * 256 * 64);   // chunk-local
    float* out3 = alloc((size_t)BB * HEADS * 256 * 64);   // both chunks
    u16* k_l16  = (u16*)alloc(524288);   // both chunks (1,048,576 u16)
    u16* w216   = (u16*)alloc(524288);   // both chunks
    float* bag  = alloc(8 * 512);
    float* xn   = alloc((size_t)MAXNN * 512);
    float* hh1  = alloc((size_t)MAXNN * 256);
    float* gbuf = alloc((size_t)MAXNN * 256);
    float* hh2  = alloc(MAXNN * 2);
    float* dinv = alloc(MAXNN);
    float* wgt  = alloc(MAXNN * KNN);
    int*   idxb = (int*)alloc(MAXNN * KNN);
    float* pvp   = alloc((size_t)32 * 256 * 8 * 64);
    float* pstat = alloc((size_t)32 * 256 * 16);
    float* attn2f = alloc(4194304);      // 64 batches x 65536 f32
    float* zF2    = alloc(4194304);      // 64 batches x 65536 f32
    u16* xp16  = (u16*)alloc(3145728);
    u16* at16  = (u16*)alloc(3145728);
    u16* a2b   = (u16*)alloc(2097152);   // 64 x 65536 u16
    u16* z16A  = (u16*)alloc(2097152);
    u16* z16B  = (u16*)alloc(2097152);
    u16* xz16  = (u16*)alloc(2097152);
    u16* p116  = (u16*)alloc(2097152);
    u16* p216  = (u16*)alloc(2097152);
    u16* fc1t  = (u16*)alloc(131072);
    u16* qkvt0 = (u16*)alloc(393216);
    u16* outt0 = (u16*)alloc(131072);
    u16* qkvt1 = (u16*)alloc(393216);
    u16* outt1 = (u16*)alloc(131072);

    // PPEG ft (24.92M f32) overlays q16+k16+v16 span (31.46M f32) — dead between layers
    float* ft = (float*)q16;
    const size_t QVOFF = (size_t)CH * HEADS * NPAD * 64;      // 12,582,912 u16 per chunk (q/v)
    const size_t LOFF  = (size_t)CH * HEADS * 256 * 64;       // 524,288 per chunk (k_l16/w216/out3)
    const size_t A2OFF = (size_t)32 * 65536;                  // per chunk (attn2/a2b)

    // preconvert/transpose all weights to bf16
    k_wconv<<<dim3(8, 8), 256, 0, stream>>>(fc1_w, 512, fc1t);
    k_wconv<<<dim3(24, 8), 256, 0, stream>>>(lp[0][2], 1536, qkvt0);
    k_wconv<<<dim3(8, 8), 256, 0, stream>>>(lp[0][3], 512, outt0);
    k_wconv<<<dim3(24, 8), 256, 0, stream>>>(lp[1][2], 1536, qkvt1);
    k_wconv<<<dim3(8, 8), 256, 0, stream>>>(lp[1][3], 512, outt1);

    // fc1 + relu -> h rows 1..6000, then wrap rows + cls
    k_gemm<1><<<dim3(4, 376), 256, 0, stream>>>(x, nullptr, fc1t, fc1_b, BB * NINST, 0,
                                                h, nullptr, nullptr, nullptr);
    k_fixup<<<dim3(BB, 85), 256, 0, stream>>>(h, cls);

    for (int l = 0; l < 2; ++l) {
        const float* ln_g  = lp[l][0];
        const float* ln_b  = lp[l][1];
        const u16* qkvt    = l == 0 ? qkvt0 : qkvt1;
        const u16* outt    = l == 0 ? outt0 : outt1;
        const float* out_b = lp[l][4];
        const float* res_w = lp[l][5];
        const float* res_b = lp[l][6];

        k_lnstat<<<BB * NTOK, 256, 0, stream>>>(h, lnstat);
        // phase A: per chunk qkv + attn3 + attn2
        for (int c = 0; c < NCHUNK; ++c) {
            int b0 = c * CH;
            k_lnbf<<<CH * NPAD, 256, 0, stream>>>(h, lnstat, ln_g, ln_b, b0, xp16);
            k_gemm<2><<<dim3(12, 192), 256, 0, stream>>>(nullptr, xp16, qkvt, nullptr, CH * NPAD, b0,
                                                         nullptr, q16 + c * QVOFF, k16, v16 + c * QVOFF);
            k_landmark<<<32 * 256, 64, 0, stream>>>(q16 + c * QVOFF, k16, q_l, k_l, k_l16 + c * LOFF);
            k_attn3_part<<<dim3(32, 4, 8), 256, 0, stream>>>(q_l, k16, v16 + c * QVOFF, pvp, pstat);
            k_attn3_comb<<<2048, 256, 0, stream>>>(pvp, pstat, out3 + c * LOFF);
            k_attn2<<<32 * 256, 256, 0, stream>>>(q_l, k_l, attn2f + c * A2OFF, a2b + c * A2OFF);
        }
        // batched pinv (64 batches = both chunks)
        k_pinv_init<<<64, 256, 0, stream>>>(attn2f, z16A);
        u16* zc16 = z16A; u16* zn16 = z16B;
        for (int it = 0; it < 6; ++it) {
            k_bgemm_b16<<<dim3(64, 4, 4), 256, 0, stream>>>(a2b, zc16, xz16, nullptr, 0.f, 1.f);
            k_bgemm_b16<<<dim3(64, 4, 4), 256, 0, stream>>>(xz16, xz16, p116, nullptr, 7.f, -1.f);
            k_bgemm_b16<<<dim3(64, 4, 4), 256, 0, stream>>>(xz16, p116, p216, nullptr, 15.f, -1.f);
            if (it < 5) {
                k_bgemm_b16<<<dim3(64, 4, 4), 256, 0, stream>>>(zc16, p216, zn16, nullptr, 3.25f, -0.25f);
                u16* tmp = zc16; zc16 = zn16; zn16 = tmp;
            } else {
                k_bgemm_b16<<<dim3(64, 4, 4), 256, 0, stream>>>(zc16, p216, nullptr, zF2, 3.25f, -0.25f);
            }
        }
        k_bgemm<<<dim3(64, 4, 1), 256, 0, stream>>>(zF2, out3, nullptr, w216, 64, 0.f, 1.f);
        // phase B: per chunk attn1 + proj
        for (int c = 0; c < NCHUNK; ++c) {
            int b0 = c * CH;
            k_attn1res<<<dim3(32, 96), 256, 0, stream>>>(q16 + c * QVOFF, k_l16 + c * LOFF,
                                                         w216 + c * LOFF, v16 + c * QVOFF,
                                                         res_w, res_b, at16);
            k_gemm<3><<<dim3(4, 192), 256, 0, stream>>>(nullptr, at16, outt, out_b, CH * NTOK, b0,
                                                        h, nullptr, nullptr, nullptr);
        }
        if (l == 0) {
            k_tr_fwd<<<dim3(96, 8, BB), 256, 0, stream>>>(h, ft);
            k_ppeg_t<<<BB * 512, 256, 0, stream>>>(ft, w7, b7, w5, b5, w3, b3);
            k_tr_bwd<<<dim3(96, 8, BB), 256, 0, stream>>>(ft, h);
        }
    }

    k_bag<<<BB, 256, 0, stream>>>(h, lnf_g, lnf_b, bag);
    k_mlp<<<1, 64, 0, stream>>>(bag, fc2w, fc2b, out);
    k_xcat<<<MAXNN, 256, 0, stream>>>(bag, reh, xn);
    k_sim_topk<<<MAXNN, 256, 0, stream>>>(xn, idxb, wgt, dinv);
    k_hh1<<<MAXNN, 256, 0, stream>>>(bag, gw1, hh1);
    k_g1<<<MAXNN, 256, 0, stream>>>(hh1, idxb, wgt, dinv, gb1, gbuf);
    k_hh2<<<MAXNN, 256, 0, stream>>>(gbuf, gw2, hh2);
    k_gout<<<1, 64, 0, stream>>>(hh2, idxb, wgt, dinv, gb2, out);
}

// Round 25
// 2528.668 us; speedup vs baseline: 1.0112x; 1.0089x over previous
//
#include <hip/hip_runtime.h>
#include <math.h>

#define DD 512
#define HEADS 8
#define DHD 64
#define MM 256
#define BB 8
#define CH 4
#define NCHUNK 2
#define NINST 6000
#define SIDE 78
#define PSIDE 84
#define NSQ 6084
#define NTOK 6085
#define PADF 59
#define NPAD 6144
#define LMM 24
#define RESK 33
#define MAXNN 520
#define KNN 12

typedef unsigned short u16;
typedef __attribute__((ext_vector_type(8))) short short8;
typedef __attribute__((ext_vector_type(4))) float f32x4;

__device__ __forceinline__ u16 f2bf(float f) {
    unsigned u = __float_as_uint(f);
    u += 0x7FFF + ((u >> 16) & 1);
    return (u16)(u >> 16);
}
__device__ __forceinline__ float bf2f(u16 v) {
    return __uint_as_float(((unsigned)v) << 16);
}

// async global->LDS, 16B per lane, wave-uniform LDS base
#define GLD_LDS16(src, dst) __builtin_amdgcn_global_load_lds( \
    (const __attribute__((address_space(1))) void*)(src),     \
    (__attribute__((address_space(3))) void*)(dst), 16, 0, 0)

// ---------------- reduction helpers (blockDim == 256 only) ----------------
__device__ __forceinline__ float blockReduceSum(float v, float* red) {
    int t = threadIdx.x;
    red[t] = v; __syncthreads();
    #pragma unroll
    for (int s = 128; s > 0; s >>= 1) { if (t < s) red[t] += red[t + s]; __syncthreads(); }
    float r = red[0]; __syncthreads();
    return r;
}
__device__ __forceinline__ float blockReduceMax(float v, float* red) {
    int t = threadIdx.x;
    red[t] = v; __syncthreads();
    #pragma unroll
    for (int s = 128; s > 0; s >>= 1) { if (t < s) red[t] = fmaxf(red[t], red[t + s]); __syncthreads(); }
    float r = red[0]; __syncthreads();
    return r;
}

// ---------------- diagnostic ----------------
__global__ void k_diag(float* __restrict__ out, float v) {
    int t = threadIdx.x;
    if (t < 32) out[t] = v;
}

// ---------------- weight transpose+convert: W[k][N] f32 -> Wt[n][512] bf16 ----------------
__global__ __launch_bounds__(256) void k_wconv(const float* __restrict__ W, int N, u16* __restrict__ Wt)
{
    __shared__ float tile[64][68];
    int n0 = blockIdx.x * 64, k0 = blockIdx.y * 64;
    int t = threadIdx.x;
    #pragma unroll
    for (int i = 0; i < 4; ++i) {
        int kr = (t >> 4) + i * 16, nc = (t & 15) * 4;
        *(float4*)&tile[kr][nc] = *(const float4*)&W[(size_t)(k0 + kr) * N + n0 + nc];
    }
    __syncthreads();
    int nr = t >> 2, kc = (t & 3) * 16;
    __align__(16) u16 tmp[16];
    #pragma unroll
    for (int j = 0; j < 16; ++j) tmp[j] = f2bf(tile[kc + j][nr]);
    *(uint4*)&Wt[(size_t)(n0 + nr) * 512 + k0 + kc]     = *(uint4*)&tmp[0];
    *(uint4*)&Wt[(size_t)(n0 + nr) * 512 + k0 + kc + 8] = *(uint4*)&tmp[8];
}

// ---------------- per-row LN stats ----------------
__global__ __launch_bounds__(256) void k_lnstat(const float* __restrict__ h, float* __restrict__ st) {
    __shared__ float red[256];
    int row = blockIdx.x;
    int t = threadIdx.x;
    const float* src = h + (size_t)row * 512;
    float x0 = src[t], x1 = src[t + 256];
    float mean = blockReduceSum(x0 + x1, red) * (1.f / 512.f);
    float d0 = x0 - mean, d1 = x1 - mean;
    float var = blockReduceSum(d0 * d0 + d1 * d1, red) * (1.f / 512.f);
    if (t == 0) { st[(size_t)row * 2] = mean; st[(size_t)row * 2 + 1] = 1.f / sqrtf(var + 1e-5f); }
}

// ---------------- LN'd + front-padded activations as bf16 (chunk-local) ----------------
__global__ __launch_bounds__(256) void k_lnbf(const float* __restrict__ h,
    const float* __restrict__ lnstat, const float* __restrict__ g,
    const float* __restrict__ be, int b0, u16* __restrict__ xp)
{
    int rowc = blockIdx.x;
    int b2 = rowc / NPAD, n2 = rowc - b2 * NPAD;
    int t = threadIdx.x;
    u16* dst = xp + (size_t)rowc * 512;
    int c = t * 2;
    if (n2 < PADF) { *(unsigned*)&dst[c] = 0u; return; }
    size_t ridx = (size_t)(b0 + b2) * NTOK + (n2 - PADF);
    const float* src = h + ridx * 512;
    float mu = lnstat[ridx * 2], rs = lnstat[ridx * 2 + 1];
    float v0 = (src[c] - mu) * rs * g[c] + be[c];
    float v1 = (src[c + 1] - mu) * rs * g[c + 1] + be[c + 1];
    u16 p[2] = { f2bf(v0), f2bf(v1) };
    *(unsigned*)&dst[c] = *(unsigned*)p;
}

// ---------------- MFMA bf16 GEMM, K=512, tile 128x128, BK=32; XCD swizzle ----------------
template<int MODE>
__global__ __launch_bounds__(256) void k_gemm(
    const float* __restrict__ A, const u16* __restrict__ A16,
    const u16* __restrict__ Wt, const float* __restrict__ bias,
    int rows, int b0,
    float* __restrict__ hbuf, u16* __restrict__ qb, u16* __restrict__ kb,
    u16* __restrict__ vb)
{
    __shared__ __align__(16) u16 As[128][32];
    __shared__ __align__(16) u16 Bs[128][32];
    int t = threadIdx.x;
    int nwg = gridDim.x * gridDim.y;
    int hid = blockIdx.y * gridDim.x + blockIdx.x;
    int per = nwg >> 3;
    int logical = (hid & 7) * per + (hid >> 3);
    int cx = logical % gridDim.x;
    int ry = logical / gridDim.x;
    int r0 = ry * 128, c0 = cx * 128;
    int w = t >> 6, l = t & 63, lr = l & 15, lg = l >> 4;

    int ch0  = w * 2;
    int crow0 = ch0 * 16 + (l >> 2);
    int ccol  = (l & 3) * 8;

    const u16* bsrc0 = Wt + (size_t)(c0 + crow0) * 512 + ccol;
    const u16* bsrc1 = bsrc0 + (size_t)16 * 512;

    const u16* asrc0 = nullptr; const u16* asrc1 = nullptr;
    if (MODE == 2) {
        asrc0 = A16 + (size_t)(r0 + crow0) * 512 + ccol;
        asrc1 = asrc0 + (size_t)16 * 512;
    } else if (MODE == 3) {
        int gr0 = r0 + crow0;
        int b20 = gr0 / NTOK, r20 = gr0 - b20 * NTOK;
        asrc0 = A16 + ((size_t)b20 * NPAD + r20 + PADF) * 512 + ccol;
        int gr1 = gr0 + 16;
        int b21 = gr1 / NTOK, r21 = gr1 - b21 * NTOK;
        asrc1 = A16 + ((size_t)b21 * NPAD + r21 + PADF) * 512 + ccol;
    }

    int srow = t >> 1, sks = (t & 1) * 16;
    int grow = r0 + srow;
    bool rowok = grow < rows;

    f32x4 acc[2][8];
    #pragma unroll
    for (int i = 0; i < 2; ++i)
        #pragma unroll
        for (int j = 0; j < 8; ++j) acc[i][j] = (f32x4){0.f, 0.f, 0.f, 0.f};

    for (int k0 = 0; k0 < 512; k0 += 32) {
        if (MODE == 1) {
            if (rowok) {
                __align__(16) u16 tmp[16];
                const float* src = A + (size_t)grow * 512 + k0 + sks;
                #pragma unroll
                for (int i = 0; i < 4; ++i) {
                    float4 v4 = *(const float4*)(src + i * 4);
                    tmp[i*4+0] = f2bf(v4.x); tmp[i*4+1] = f2bf(v4.y);
                    tmp[i*4+2] = f2bf(v4.z); tmp[i*4+3] = f2bf(v4.w);
                }
                *(uint4*)&As[srow][sks]     = *(uint4*)&tmp[0];
                *(uint4*)&As[srow][sks + 8] = *(uint4*)&tmp[8];
            } else {
                *(uint4*)&As[srow][sks]     = make_uint4(0, 0, 0, 0);
                *(uint4*)&As[srow][sks + 8] = make_uint4(0, 0, 0, 0);
            }
        } else {
            GLD_LDS16(asrc0 + k0, &As[ch0 * 16][0]);
            GLD_LDS16(asrc1 + k0, &As[ch0 * 16 + 16][0]);
        }
        GLD_LDS16(bsrc0 + k0, &Bs[ch0 * 16][0]);
        GLD_LDS16(bsrc1 + k0, &Bs[ch0 * 16 + 16][0]);
        __syncthreads();
        short8 a0 = *(const short8*)&As[w * 32 + lr][lg * 8];
        short8 a1 = *(const short8*)&As[w * 32 + 16 + lr][lg * 8];
        #pragma unroll
        for (int nf = 0; nf < 8; ++nf) {
            short8 bf = *(const short8*)&Bs[nf * 16 + lr][lg * 8];
            acc[0][nf] = __builtin_amdgcn_mfma_f32_16x16x32_bf16(a0, bf, acc[0][nf], 0, 0, 0);
            acc[1][nf] = __builtin_amdgcn_mfma_f32_16x16x32_bf16(a1, bf, acc[1][nf], 0, 0, 0);
        }
        __syncthreads();
    }
    #pragma unroll
    for (int mf = 0; mf < 2; ++mf) {
        #pragma unroll
        for (int r = 0; r < 4; ++r) {
            int row = r0 + w * 32 + mf * 16 + lg * 4 + r;
            if (row >= rows) continue;
            int b2, r2;
            if (MODE == 1)      { b2 = row / NINST; r2 = row - b2 * NINST; }
            else if (MODE == 2) { b2 = row / NPAD;  r2 = row - b2 * NPAD; }
            else                { b2 = row / NTOK;  r2 = row - b2 * NTOK; }
            #pragma unroll
            for (int nf = 0; nf < 8; ++nf) {
                int col = c0 + nf * 16 + lr;
                float val = acc[mf][nf][r];
                if (MODE == 1) {
                    val += bias[col];
                    val = fmaxf(val, 0.f);
                    hbuf[((size_t)b2 * NTOK + 1 + r2) * 512 + col] = val;
                } else if (MODE == 2) {
                    int which = col >> 9, head = (col >> 6) & 7, dh = col & 63;
                    u16* dst = which == 0 ? qb : (which == 1 ? kb : vb);
                    if (which == 0) val *= 0.125f;
                    dst[(((size_t)b2 * HEADS + head) * NPAD + r2) * 64 + dh] = f2bf(val);
                } else {
                    size_t o = ((size_t)(b0 + b2) * NTOK + r2) * 512 + col;
                    hbuf[o] += val + bias[col];
                }
            }
        }
    }
}

// ---------------- batched 256xNcols f32 GEMM (K=256), optional bf16 out ----------------
__global__ __launch_bounds__(256) void k_bgemm(
    const float* __restrict__ A, const float* __restrict__ B,
    float* __restrict__ C, u16* __restrict__ C16, int ncols, float coefA, float coefAB)
{
    __shared__ float As[16][68];
    __shared__ float Bs[16][68];
    int t = threadIdx.x;
    int bat = blockIdx.x, rt = blockIdx.y, ct = blockIdx.z;
    const float* Ab = A + (size_t)bat * 65536;
    const float* Bb = B + (size_t)bat * 256 * ncols;
    int r0 = rt * 64, c0 = ct * 64;
    int tr = t >> 4, tc = t & 15, lr = t >> 2, lk4 = (t & 3) << 2;
    int wkk = t >> 4, wcc = (t & 15) << 2;
    float acc[4][4] = {{0.f}};
    for (int k0 = 0; k0 < 256; k0 += 16) {
        float4 av = *(const float4*)(Ab + (size_t)(r0 + lr) * 256 + k0 + lk4);
        As[lk4 + 0][lr] = av.x;
        As[lk4 + 1][lr] = av.y;
        As[lk4 + 2][lr] = av.z;
        As[lk4 + 3][lr] = av.w;
        *(float4*)&Bs[wkk][wcc] = *(const float4*)(Bb + (size_t)(k0 + wkk) * ncols + c0 + wcc);
        __syncthreads();
        #pragma unroll
        for (int kk = 0; kk < 16; ++kk) {
            float a[4], b4[4];
            *(float4*)a  = *(float4*)&As[kk][tr << 2];
            *(float4*)b4 = *(float4*)&Bs[kk][tc << 2];
            #pragma unroll
            for (int i2 = 0; i2 < 4; ++i2)
                #pragma unroll
                for (int j2 = 0; j2 < 4; ++j2)
                    acc[i2][j2] += a[i2] * b4[j2];
        }
        __syncthreads();
    }
    #pragma unroll
    for (int i2 = 0; i2 < 4; ++i2) {
        int row = r0 + (tr << 2) + i2;
        #pragma unroll
        for (int j2 = 0; j2 < 4; ++j2) {
            int col = c0 + (tc << 2) + j2;
            float val = coefAB * acc[i2][j2];
            if (coefA != 0.f) val += coefA * Ab[(size_t)row * 256 + col];
            size_t o = (size_t)bat * 256 * ncols + (size_t)row * ncols + col;
            if (C16) C16[o] = f2bf(val);
            else     C[o] = val;
        }
    }
}

// ---------------- batched MFMA GEMM, bf16 in / bf16-or-f32 out (K=256, N=256) ----------------
__global__ __launch_bounds__(256) void k_bgemm_b16(
    const u16* __restrict__ A, const u16* __restrict__ B,
    u16* __restrict__ C, float* __restrict__ Cf, float coefA, float coefAB)
{
    __shared__ __align__(16) u16 As[64][40];
    __shared__ __align__(16) u16 Bs[64][40];
    int t = threadIdx.x;
    int bat = blockIdx.x, rt = blockIdx.y, ct = blockIdx.z;
    const u16* Ab = A + (size_t)bat * 65536;
    const u16* Bb = B + (size_t)bat * 65536;
    int r0 = rt * 64, c0 = ct * 64;
    int w = t >> 6, l = t & 63, lr = l & 15, lg = l >> 4;
    int am = t >> 2, ak = (t & 3) * 8;
    int bn = t & 63, bk0 = t >> 6 << 3;
    f32x4 acc[4];
    #pragma unroll
    for (int j = 0; j < 4; ++j) acc[j] = (f32x4){0.f, 0.f, 0.f, 0.f};
    for (int k0 = 0; k0 < 256; k0 += 32) {
        *(uint4*)&As[am][ak] = *(const uint4*)&Ab[(size_t)(r0 + am) * 256 + k0 + ak];
        __align__(16) u16 tb[8];
        #pragma unroll
        for (int i = 0; i < 8; ++i)
            tb[i] = Bb[(size_t)(k0 + bk0 + i) * 256 + c0 + bn];
        *(uint4*)&Bs[bn][bk0] = *(uint4*)&tb[0];
        __syncthreads();
        short8 a = *(const short8*)&As[w * 16 + lr][lg * 8];
        #pragma unroll
        for (int nf = 0; nf < 4; ++nf) {
            short8 bf = *(const short8*)&Bs[nf * 16 + lr][lg * 8];
            acc[nf] = __builtin_amdgcn_mfma_f32_16x16x32_bf16(a, bf, acc[nf], 0, 0, 0);
        }
        __syncthreads();
    }
    #pragma unroll
    for (int r = 0; r < 4; ++r) {
        int row = r0 + w * 16 + lg * 4 + r;
        #pragma unroll
        for (int nf = 0; nf < 4; ++nf) {
            int col = c0 + nf * 16 + lr;
            float val = coefAB * acc[nf][r];
            if (coefA != 0.f) val += coefA * bf2f(Ab[(size_t)row * 256 + col]);
            if (Cf) Cf[(size_t)bat * 65536 + (size_t)row * 256 + col] = val;
            else    C[(size_t)bat * 65536 + (size_t)row * 256 + col] = f2bf(val);
        }
    }
}

// ---------------- wrap rows + cls token ----------------
__global__ void k_fixup(float* __restrict__ h, const float* __restrict__ cls)
{
    int b = blockIdx.x, r = blockIdx.y, t = threadIdx.x;
    float* dst; const float* src;
    if (r < 84) {
        dst = h + ((size_t)b * NTOK + 6001 + r) * 512;
        src = h + ((size_t)b * NTOK + 1 + r) * 512;
    } else {
        dst = h + (size_t)b * NTOK * 512;
        src = cls;
    }
    dst[t] = src[t]; dst[t + 256] = src[t + 256];
}

// ---------------- landmarks (bf16 in, f32 + bf16 out) ----------------
__global__ void k_landmark(const u16* __restrict__ q, const u16* __restrict__ k,
                           float* __restrict__ q_l, float* __restrict__ k_l,
                           u16* __restrict__ k_l16)
{
    int bhm = blockIdx.x;
    int d = threadIdx.x;
    int bh = bhm >> 8, m = bhm & 255;
    const u16* qs = q + ((size_t)bh * NPAD + m * LMM) * 64 + d;
    const u16* ks = k + ((size_t)bh * NPAD + m * LMM) * 64 + d;
    float sq = 0.f, sk = 0.f;
    #pragma unroll
    for (int j = 0; j < LMM; ++j) { sq += bf2f(qs[(size_t)j * 64]); sk += bf2f(ks[(size_t)j * 64]); }
    float kv = sk * (1.f / 24.f);
    q_l[(size_t)bhm * 64 + d] = sq * (1.f / 24.f);
    k_l[(size_t)bhm * 64 + d] = kv;
    k_l16[(size_t)bhm * 64 + d] = f2bf(kv);
}

// ---------------- attn2 = softmax(q_l @ k_l^T), f32 + bf16 outputs ----------------
__global__ __launch_bounds__(256) void k_attn2(const float* __restrict__ q_l,
    const float* __restrict__ k_l, float* __restrict__ attn2, u16* __restrict__ a2b)
{
    __shared__ float ql[64];
    __shared__ float red[256];
    int bh = blockIdx.x >> 8, i = blockIdx.x & 255;
    int t = threadIdx.x;
    if (t < 64) ql[t] = q_l[((size_t)(bh * 256 + i)) * 64 + t];
    __syncthreads();
    const float4* kr = (const float4*)(k_l + ((size_t)bh * 256 + t) * 64);
    float s = 0.f;
    #pragma unroll
    for (int d4 = 0; d4 < 16; ++d4) {
        float4 kv = kr[d4];
        s += ql[d4 * 4] * kv.x + ql[d4 * 4 + 1] * kv.y + ql[d4 * 4 + 2] * kv.z + ql[d4 * 4 + 3] * kv.w;
    }
    float mx = blockReduceMax(s, red);
    float e = expf(s - mx);
    float S = blockReduceSum(e, red);
    float p = e / S;
    size_t o = ((size_t)(bh * 256 + i)) * 256 + t;
    attn2[o] = p;
    a2b[o] = f2bf(p);
}

// ---------------- pinv init -> bf16 ----------------
__global__ __launch_bounds__(256) void k_pinv_init(const float* __restrict__ x, u16* __restrict__ z16)
{
    __shared__ float red[256];
    int bh = blockIdx.x, t = threadIdx.x;
    const float* xb = x + (size_t)bh * 65536;
    float rs = 0.f;
    for (int j = 0; j < 256; ++j) rs += xb[t * 256 + j];
    float colv = blockReduceMax(rs, red);
    float cs = 0.f;
    for (int i2 = 0; i2 < 256; ++i2) cs += xb[i2 * 256 + t];
    float rowv = blockReduceMax(cs, red);
    float scale = 1.f / (colv * rowv);
    u16* zb = z16 + (size_t)bh * 65536;
    for (int i2 = 0; i2 < 256; ++i2)
        zb[(size_t)i2 * 256 + t] = f2bf(xb[(size_t)t * 256 + i2] * scale);
}

// ---------------- attn3 @ v : flash MFMA-bf16 partial kernel (bf16 K/V) ----------------
__global__ __launch_bounds__(256) void k_attn3_part(
    const float* __restrict__ q_l, const u16* __restrict__ kbuf,
    const u16* __restrict__ vbuf, float* __restrict__ pv, float* __restrict__ pstat)
{
    __shared__ __align__(16) u16 Qb[64][72];
    __shared__ __align__(16) u16 Kb[64][72];
    __shared__ __align__(16) u16 Pb[64][72];
    int bh = blockIdx.x, mb = blockIdx.y, ns = blockIdx.z;
    int t = threadIdx.x, w = t >> 6, l = t & 63, lr = l & 15, lg = l >> 4;
    {
        int srow = t >> 2, sd = (t & 3) * 16;
        const float* src = q_l + ((size_t)bh * 256 + mb * 64 + srow) * 64 + sd;
        __align__(16) u16 tmp[16];
        #pragma unroll
        for (int i = 0; i < 16; ++i) tmp[i] = f2bf(src[i]);
        *(uint4*)&Qb[srow][sd]     = *(uint4*)&tmp[0];
        *(uint4*)&Qb[srow][sd + 8] = *(uint4*)&tmp[8];
    }
    f32x4 acc[4];
    #pragma unroll
    for (int j = 0; j < 4; ++j) acc[j] = (f32x4){0.f, 0.f, 0.f, 0.f};
    float m_run[4], s_run[4];
    #pragma unroll
    for (int i = 0; i < 4; ++i) { m_run[i] = -INFINITY; s_run[i] = 0.f; }
    const int n00 = ns * 768;
    for (int tile = 0; tile < 12; ++tile) {
        int nb = n00 + tile * 64;
        __syncthreads();
        {
            int srow = t >> 2, sd = (t & 3) * 16;
            const u16* src = kbuf + ((size_t)bh * NPAD + nb + srow) * 64 + sd;
            *(uint4*)&Kb[srow][sd]     = *(const uint4*)&src[0];
            *(uint4*)&Kb[srow][sd + 8] = *(const uint4*)&src[8];
        }
        __syncthreads();
        f32x4 s[4];
        #pragma unroll
        for (int j = 0; j < 4; ++j) s[j] = (f32x4){0.f, 0.f, 0.f, 0.f};
        #pragma unroll
        for (int ks = 0; ks < 64; ks += 32) {
            short8 a = *(const short8*)&Qb[w * 16 + lr][lg * 8 + ks];
            #pragma unroll
            for (int nf = 0; nf < 4; ++nf) {
                short8 bf = *(const short8*)&Kb[nf * 16 + lr][lg * 8 + ks];
                s[nf] = __builtin_amdgcn_mfma_f32_16x16x32_bf16(a, bf, s[nf], 0, 0, 0);
            }
        }
        #pragma unroll
        for (int r = 0; r < 4; ++r) {
            float lm = fmaxf(fmaxf(s[0][r], s[1][r]), fmaxf(s[2][r], s[3][r]));
            #pragma unroll
            for (int off = 1; off < 16; off <<= 1)
                lm = fmaxf(lm, __shfl_xor(lm, off, 16));
            float m_new = fmaxf(m_run[r], lm);
            float scf = expf(m_run[r] - m_new);
            s_run[r] *= scf;
            acc[0][r] *= scf; acc[1][r] *= scf; acc[2][r] *= scf; acc[3][r] *= scf;
            float p0 = expf(s[0][r] - m_new), p1 = expf(s[1][r] - m_new);
            float p2 = expf(s[2][r] - m_new), p3 = expf(s[3][r] - m_new);
            float ls = p0 + p1 + p2 + p3;
            #pragma unroll
            for (int off = 1; off < 16; off <<= 1)
                ls += __shfl_xor(ls, off, 16);
            s_run[r] += ls;
            m_run[r] = m_new;
            int prow = w * 16 + lg * 4 + r;
            Pb[prow][lr]      = f2bf(p0);
            Pb[prow][16 + lr] = f2bf(p1);
            Pb[prow][32 + lr] = f2bf(p2);
            Pb[prow][48 + lr] = f2bf(p3);
        }
        __syncthreads();
        {
            int nl = t & 63, dvb = (t >> 6) * 16;
            const u16* src = vbuf + ((size_t)bh * NPAD + nb + nl) * 64 + dvb;
            __align__(16) u16 tmp[16];
            *(uint4*)&tmp[0] = *(const uint4*)&src[0];
            *(uint4*)&tmp[8] = *(const uint4*)&src[8];
            #pragma unroll
            for (int j = 0; j < 16; ++j) Kb[dvb + j][nl] = tmp[j];
        }
        __syncthreads();
        #pragma unroll
        for (int ks = 0; ks < 64; ks += 32) {
            short8 a = *(const short8*)&Pb[w * 16 + lr][lg * 8 + ks];
            #pragma unroll
            for (int df = 0; df < 4; ++df) {
                short8 bf = *(const short8*)&Kb[df * 16 + lr][lg * 8 + ks];
                acc[df] = __builtin_amdgcn_mfma_f32_16x16x32_bf16(a, bf, acc[df], 0, 0, 0);
            }
        }
    }
    #pragma unroll
    for (int r = 0; r < 4; ++r) {
        int mloc = w * 16 + lg * 4 + r;
        size_t row = (size_t)bh * 256 + mb * 64 + mloc;
        float* dst = pv + (row * 8 + ns) * 64;
        dst[lr]      = acc[0][r];
        dst[16 + lr] = acc[1][r];
        dst[32 + lr] = acc[2][r];
        dst[48 + lr] = acc[3][r];
        if (lr == 0) { pstat[row * 16 + ns * 2] = m_run[r]; pstat[row * 16 + ns * 2 + 1] = s_run[r]; }
    }
}

// combine 8 slices -> out3
__global__ __launch_bounds__(256) void k_attn3_comb(
    const float* __restrict__ pv, const float* __restrict__ pstat, float* __restrict__ out3)
{
    size_t row = (size_t)blockIdx.x * 4 + (threadIdx.x >> 6);
    int d = threadIdx.x & 63;
    float M = -INFINITY;
    #pragma unroll
    for (int s = 0; s < 8; ++s) M = fmaxf(M, pstat[row * 16 + s * 2]);
    float num = 0.f, den = 0.f;
    #pragma unroll
    for (int s = 0; s < 8; ++s) {
        float w = expf(pstat[row * 16 + s * 2] - M);
        den += w * pstat[row * 16 + s * 2 + 1];
        num += w * pv[(row * 8 + s) * 64 + d];
    }
    out3[row * 64 + d] = num / den;
}

// ---------------- attn1 softmax @ w2 + res conv + res_b; bf16 bufv, 31KB LDS ----------------
__global__ __launch_bounds__(256) void k_attn1res(
    const u16* __restrict__ qbuf, const u16* __restrict__ k_l16,
    const u16* __restrict__ w216, const u16* __restrict__ vbuf,
    const float* __restrict__ res_w, const float* __restrict__ res_b,
    u16* __restrict__ outb16)
{
    __shared__ __align__(16) char smem[31232];
    u16 (*Qb)[72]   = (u16(*)[72])smem;
    u16 (*Kb)[72]   = (u16(*)[72])(smem + 9216);
    u16 (*Pb)[72]   = (u16(*)[72])(smem + 18432);
    float (*osm)[68] = (float(*)[68])smem;
    u16 (*bufv)[72]  = (u16(*)[72])(smem + 17408);
    __shared__ float wconv[RESK];
    int bh = blockIdx.x, nb = blockIdx.y, hh = bh & 7;
    int b2 = bh >> 3;
    int t = threadIdx.x, w = t >> 6, l = t & 63, lr = l & 15, lg = l >> 4;
    int tr = t >> 4, tc = t & 15;
    int n0 = nb * 64;
    if (t < RESK) wconv[t] = res_w[hh * RESK + t];
    {
        int srow = t >> 2, sd = (t & 3) * 16;
        const u16* src = qbuf + ((size_t)bh * NPAD + n0 + srow) * 64 + sd;
        *(uint4*)&Qb[srow][sd]     = *(const uint4*)&src[0];
        *(uint4*)&Qb[srow][sd + 8] = *(const uint4*)&src[8];
    }
    f32x4 acc[4];
    #pragma unroll
    for (int j = 0; j < 4; ++j) acc[j] = (f32x4){0.f, 0.f, 0.f, 0.f};
    float m_run[4], s_run[4];
    #pragma unroll
    for (int i = 0; i < 4; ++i) { m_run[i] = -INFINITY; s_run[i] = 0.f; }
    for (int mt = 0; mt < 4; ++mt) {
        __syncthreads();
        {
            int srow = t >> 2, sd = (t & 3) * 16;
            const u16* src = k_l16 + ((size_t)bh * 256 + mt * 64 + srow) * 64 + sd;
            *(uint4*)&Kb[srow][sd]     = *(const uint4*)&src[0];
            *(uint4*)&Kb[srow][sd + 8] = *(const uint4*)&src[8];
        }
        __syncthreads();
        f32x4 s[4];
        #pragma unroll
        for (int j = 0; j < 4; ++j) s[j] = (f32x4){0.f, 0.f, 0.f, 0.f};
        #pragma unroll
        for (int ks = 0; ks < 64; ks += 32) {
            short8 a = *(const short8*)&Qb[w * 16 + lr][lg * 8 + ks];
            #pragma unroll
            for (int nf = 0; nf < 4; ++nf) {
                short8 bf = *(const short8*)&Kb[nf * 16 + lr][lg * 8 + ks];
                s[nf] = __builtin_amdgcn_mfma_f32_16x16x32_bf16(a, bf, s[nf], 0, 0, 0);
            }
        }
        #pragma unroll
        for (int r = 0; r < 4; ++r) {
            float lm = fmaxf(fmaxf(s[0][r], s[1][r]), fmaxf(s[2][r], s[3][r]));
            #pragma unroll
            for (int off = 1; off < 16; off <<= 1)
                lm = fmaxf(lm, __shfl_xor(lm, off, 16));
            float m_new = fmaxf(m_run[r], lm);
            float scf = expf(m_run[r] - m_new);
            s_run[r] *= scf;
            acc[0][r] *= scf; acc[1][r] *= scf; acc[2][r] *= scf; acc[3][r] *= scf;
            float p0 = expf(s[0][r] - m_new), p1 = expf(s[1][r] - m_new);
            float p2 = expf(s[2][r] - m_new), p3 = expf(s[3][r] - m_new);
            float ls = p0 + p1 + p2 + p3;
            #pragma unroll
            for (int off = 1; off < 16; off <<= 1)
                ls += __shfl_xor(ls, off, 16);
            s_run[r] += ls;
            m_run[r] = m_new;
            int prow = w * 16 + lg * 4 + r;
            Pb[prow][lr]      = f2bf(p0);
            Pb[prow][16 + lr] = f2bf(p1);
            Pb[prow][32 + lr] = f2bf(p2);
            Pb[prow][48 + lr] = f2bf(p3);
        }
        __syncthreads();
        {
            int nl = t & 63, dvb = (t >> 6) * 16;
            const u16* src = w216 + ((size_t)bh * 256 + mt * 64 + nl) * 64 + dvb;
            __align__(16) u16 tmp[16];
            *(uint4*)&tmp[0] = *(const uint4*)&src[0];
            *(uint4*)&tmp[8] = *(const uint4*)&src[8];
            #pragma unroll
            for (int j = 0; j < 16; ++j) Kb[dvb + j][nl] = tmp[j];
        }
        __syncthreads();
        #pragma unroll
        for (int ks = 0; ks < 64; ks += 32) {
            short8 a = *(const short8*)&Pb[w * 16 + lr][lg * 8 + ks];
            #pragma unroll
            for (int df = 0; df < 4; ++df) {
                short8 bf = *(const short8*)&Kb[df * 16 + lr][lg * 8 + ks];
                acc[df] = __builtin_amdgcn_mfma_f32_16x16x32_bf16(a, bf, acc[df], 0, 0, 0);
            }
        }
    }
    __syncthreads();
    #pragma unroll
    for (int r = 0; r < 4; ++r) {
        float inv = 1.f / s_run[r];
        int m = w * 16 + lg * 4 + r;
        osm[m][lr]      = acc[0][r] * inv;
        osm[m][16 + lr] = acc[1][r] * inv;
        osm[m][32 + lr] = acc[2][r] * inv;
        osm[m][48 + lr] = acc[3][r] * inv;
    }
    for (int idx = t; idx < 96 * 8; idx += 256) {
        int rowl = idx >> 3, d8 = (idx & 7) * 8;
        int gn = n0 - 16 + rowl;
        uint4 v4 = make_uint4(0u, 0u, 0u, 0u);
        if (gn >= 0 && gn < NPAD)
            v4 = *(const uint4*)(vbuf + ((size_t)bh * NPAD + gn) * 64 + d8);
        *(uint4*)&bufv[rowl][d8] = v4;
    }
    __syncthreads();
    float rb = res_b[hh];
    #pragma unroll
    for (int i = 0; i < 4; ++i) {
        int rl = tr * 4 + i;
        int n = n0 + rl;
        if (n < PADF) continue;
        float4 oo = *(float4*)&osm[rl][tc * 4];
        float o0 = oo.x, o1 = oo.y, o2 = oo.z, o3 = oo.w;
        #pragma unroll
        for (int jj = 0; jj < RESK; ++jj) {
            float wj = wconv[jj];
            u16 q4[4];
            *(uint2*)q4 = *(const uint2*)&bufv[rl + jj][tc * 4];
            o0 += wj * bf2f(q4[0]); o1 += wj * bf2f(q4[1]);
            o2 += wj * bf2f(q4[2]); o3 += wj * bf2f(q4[3]);
        }
        u16 ob[4] = { f2bf(o0 + rb), f2bf(o1 + rb), f2bf(o2 + rb), f2bf(o3 + rb) };
        u16* dst = outb16 + ((size_t)b2 * NPAD + n) * 512 + hh * 64 + tc * 4;
        *(uint2*)dst = *(uint2*)ob;
    }
}

// ---------------- PPEG via transpose ----------------
__global__ __launch_bounds__(256) void k_tr_fwd(const float* __restrict__ h, float* __restrict__ ft)
{
    __shared__ float tile[64][68];
    int tt = blockIdx.x, ct8 = blockIdx.y, b = blockIdx.z;
    int t = threadIdx.x;
    int p0 = tt * 64, c0 = ct8 * 64;
    #pragma unroll
    for (int i = 0; i < 4; ++i) {
        int plr = (t >> 4) + i * 16;
        int cl = (t & 15) * 4;
        int p = p0 + plr;
        if (p < NSQ) {
            float4 v = *(const float4*)(h + ((size_t)b * NTOK + 1 + p) * 512 + c0 + cl);
            *(float4*)&tile[plr][cl] = v;
        }
    }
    __syncthreads();
    #pragma unroll
    for (int i = 0; i < 4; ++i) {
        int cl = (t >> 4) + i * 16;
        int plr = (t & 15) * 4;
        if (p0 + plr + 3 < NSQ) {
            float4 v = make_float4(tile[plr][cl], tile[plr + 1][cl], tile[plr + 2][cl], tile[plr + 3][cl]);
            *(float4*)(ft + ((size_t)b * 512 + c0 + cl) * NSQ + p0 + plr) = v;
        }
    }
}

__global__ __launch_bounds__(256) void k_tr_bwd(const float* __restrict__ ft, float* __restrict__ h)
{
    __shared__ float tile[64][68];
    int tt = blockIdx.x, ct8 = blockIdx.y, b = blockIdx.z;
    int t = threadIdx.x;
    int p0 = tt * 64, c0 = ct8 * 64;
    #pragma unroll
    for (int i = 0; i < 4; ++i) {
        int cl = (t >> 4) + i * 16;
        int plr = (t & 15) * 4;
        if (p0 + plr + 3 < NSQ) {
            float4 v = *(const float4*)(ft + ((size_t)b * 512 + c0 + cl) * NSQ + p0 + plr);
            tile[plr][cl] = v.x; tile[plr + 1][cl] = v.y;
            tile[plr + 2][cl] = v.z; tile[plr + 3][cl] = v.w;
        }
    }
    __syncthreads();
    #pragma unroll
    for (int i = 0; i < 4; ++i) {
        int plr = (t >> 4) + i * 16;
        int cl = (t & 15) * 4;
        int p = p0 + plr;
        if (p < NSQ) {
            float4 v = *(float4*)&tile[plr][cl];
            *(float4*)(h + ((size_t)b * NTOK + 1 + p) * 512 + c0 + cl) = v;
        }
    }
}

// per (b, channel) plane: combined 7x7 weights, register-blocked 4 outputs/thread
__global__ __launch_bounds__(256) void k_ppeg_t(float* __restrict__ ft,
    const float* __restrict__ w7, const float* __restrict__ b7,
    const float* __restrict__ w5, const float* __restrict__ b5,
    const float* __restrict__ w3, const float* __restrict__ b3)
{
    __shared__ __align__(16) float f[PSIDE * PSIDE];
    __shared__ float wt[49];
    int bc = blockIdx.x;
    int b = bc >> 9, c = bc & 511;
    int t = threadIdx.x;
    float* plane = ft + ((size_t)b * 512 + c) * NSQ;
    for (int i = t; i < PSIDE * PSIDE; i += 256) f[i] = 0.f;
    if (t < 49) {
        int dy = t / 7 - 3, dx = t % 7 - 3;
        float v = w7[c * 49 + t];
        if (dy >= -2 && dy <= 2 && dx >= -2 && dx <= 2) v += w5[c * 25 + (dy + 2) * 5 + (dx + 2)];
        if (dy >= -1 && dy <= 1 && dx >= -1 && dx <= 1) v += w3[c * 9 + (dy + 1) * 3 + (dx + 1)];
        wt[t] = v;
    }
    __syncthreads();
    for (int p = t; p < NSQ; p += 256) {
        int r = p / SIDE, s2 = p - r * SIDE;
        f[(r + 3) * PSIDE + s2 + 3] = plane[p];
    }
    __syncthreads();
    float bsum = b7[c] + b5[c] + b3[c];
    for (int st = t; st < SIDE * 20; st += 256) {
        int r = st / 20, s0 = (st - (st / 20) * 20) * 4;
        float a0 = bsum + f[(r + 3) * PSIDE + s0 + 3];
        float a1 = bsum + f[(r + 3) * PSIDE + s0 + 4];
        float a2 = bsum + f[(r + 3) * PSIDE + s0 + 5];
        float a3 = bsum + f[(r + 3) * PSIDE + s0 + 6];
        #pragma unroll
        for (int dyy = 0; dyy < 7; ++dyy) {
            const float* rowp = &f[(r + dyy) * PSIDE + s0];
            float win[12];
            *(float4*)&win[0] = *(const float4*)&rowp[0];
            *(float4*)&win[4] = *(const float4*)&rowp[4];
            *(float4*)&win[8] = *(const float4*)&rowp[8];
            const float* wr = &wt[dyy * 7];
            #pragma unroll
            for (int dxx = 0; dxx < 7; ++dxx) {
                float wj = wr[dxx];
                a0 += win[0 + dxx] * wj;
                a1 += win[1 + dxx] * wj;
                a2 += win[2 + dxx] * wj;
                a3 += win[3 + dxx] * wj;
            }
        }
        int base = r * SIDE + s0;
        plane[base] = a0;
        if (s0 + 1 < SIDE) plane[base + 1] = a1;
        if (s0 + 2 < SIDE) plane[base + 2] = a2;
        if (s0 + 3 < SIDE) plane[base + 3] = a3;
    }
}

// ---------------- final LN of cls token ----------------
__global__ __launch_bounds__(256) void k_bag(const float* __restrict__ h,
    const float* __restrict__ g, const float* __restrict__ be, float* __restrict__ bag)
{
    __shared__ float red[256];
    int b = blockIdx.x, t = threadIdx.x;
    const float* src = h + (size_t)b * NTOK * 512;
    float x0 = src[t], x1 = src[t + 256];
    float mean = blockReduceSum(x0 + x1, red) * (1.f / 512.f);
    float d0 = x0 - mean, d1 = x1 - mean;
    float var = blockReduceSum(d0 * d0 + d1 * d1, red) * (1.f / 512.f);
    float rs = 1.f / sqrtf(var + 1e-5f);
    bag[b * 512 + t]       = d0 * rs * g[t] + be[t];
    bag[b * 512 + t + 256] = d1 * rs * g[t + 256] + be[t + 256];
}

__global__ void k_mlp(const float* __restrict__ bag, const float* __restrict__ fc2w,
                      const float* __restrict__ fc2b, float* __restrict__ out)
{
    int t = threadIdx.x;
    if (t < 16) {
        int b = t >> 1, c = t & 1;
        float val = fc2b[c];
        for (int k2 = 0; k2 < 512; ++k2) val += bag[b * 512 + k2] * fc2w[k2 * 2 + c];
        out[b * 2 + c] = val;
    }
}

__global__ __launch_bounds__(256) void k_xcat(const float* __restrict__ bag,
    const float* __restrict__ reh, float* __restrict__ xn)
{
    __shared__ float red[256];
    int i = blockIdx.x, t = threadIdx.x;
    const float* src = (i < BB) ? (bag + (size_t)i * 512) : (reh + (size_t)(i - BB) * 512);
    float x0 = src[t], x1 = src[t + 256];
    float nrm = sqrtf(blockReduceSum(x0 * x0 + x1 * x1, red));
    float inv = 1.f / (nrm + 1e-8f);
    xn[(size_t)i * 512 + t]       = x0 * inv;
    xn[(size_t)i * 512 + t + 256] = x1 * inv;
}

// ---------------- sim row + top-12 (coalesced per-wave dot + shfl argmax) ----------------
__global__ __launch_bounds__(256) void k_sim_topk(const float* __restrict__ xn,
    int* __restrict__ idxb, float* __restrict__ wgt, float* __restrict__ dinvb)
{
    __shared__ float xi[512];
    __shared__ float s[MAXNN];
    __shared__ float wv[4];
    __shared__ int wi_[4];
    int i = blockIdx.x, t = threadIdx.x;
    int w = t >> 6, l = t & 63;
    xi[t] = xn[(size_t)i * 512 + t];
    xi[t + 256] = xn[(size_t)i * 512 + t + 256];
    __syncthreads();
    // wave w handles rows j = w, w+4, ...; lanes split the 512-dim dot (coalesced)
    const float4* xiv = (const float4*)xi;
    float4 u0 = xiv[l * 2], u1 = xiv[l * 2 + 1];
    for (int j = w; j < MAXNN; j += 4) {
        const float4* xj = (const float4*)(xn + (size_t)j * 512);
        float4 v0 = xj[l * 2], v1 = xj[l * 2 + 1];
        float a = u0.x * v0.x + u0.y * v0.y + u0.z * v0.z + u0.w * v0.w
                + u1.x * v1.x + u1.y * v1.y + u1.z * v1.z + u1.w * v1.w;
        #pragma unroll
        for (int off = 32; off > 0; off >>= 1) a += __shfl_xor(a, off);
        if (l == 0) s[j] = a - (j == i ? 1e9f : 0.f);
    }
    __syncthreads();
    float degsum = 0.f;
    for (int kk = 0; kk < KNN; ++kk) {
        float bv = -INFINITY; int bi = MAXNN;
        for (int j = t; j < MAXNN; j += 256) {
            float vv = s[j];
            if (vv > bv) { bv = vv; bi = j; }
        }
        // 64-lane wave argmax (smaller index wins ties)
        #pragma unroll
        for (int off = 32; off > 0; off >>= 1) {
            float ov = __shfl_down(bv, off);
            int   oi = __shfl_down(bi, off);
            if (ov > bv || (ov == bv && oi < bi)) { bv = ov; bi = oi; }
        }
        if ((t & 63) == 0) { wv[t >> 6] = bv; wi_[t >> 6] = bi; }
        __syncthreads();
        if (t == 0) {
            bv = wv[0]; bi = wi_[0];
            #pragma unroll
            for (int q = 1; q < 4; ++q)
                if (wv[q] > bv || (wv[q] == bv && wi_[q] < bi)) { bv = wv[q]; bi = wi_[q]; }
            idxb[i * KNN + kk] = bi;
            float ww = fmaxf(bv, 0.f);
            wgt[i * KNN + kk] = ww;
            degsum += ww;
            s[bi] = -INFINITY;
            if (kk == KNN - 1) dinvb[i] = 1.f / sqrtf(1.f + degsum);
        }
        __syncthreads();
    }
}

// ---------------- GCN ----------------
__global__ __launch_bounds__(256) void k_hh1(const float* __restrict__ bag,
    const float* __restrict__ w1, float* __restrict__ hh1)
{
    int i = blockIdx.x, t = threadIdx.x;
    if (i >= BB) { hh1[(size_t)i * 256 + t] = 0.f; return; }
    float acc = 0.f;
    for (int k2 = 0; k2 < 512; ++k2) acc += bag[i * 512 + k2] * w1[(size_t)k2 * 256 + t];
    hh1[(size_t)i * 256 + t] = acc;
}

__global__ __launch_bounds__(256) void k_g1(const float* __restrict__ hh1,
    const int* __restrict__ idxb, const float* __restrict__ wgt,
    const float* __restrict__ dinvb, const float* __restrict__ b1, float* __restrict__ g)
{
    __shared__ float cf[KNN];
    __shared__ int src[KNN];
    int i = blockIdx.x, t = threadIdx.x;
    if (t < KNN) {
        int s2 = idxb[i * KNN + t];
        src[t] = s2;
        cf[t] = wgt[i * KNN + t] * dinvb[s2] * dinvb[i];
    }
    __syncthreads();
    float di = dinvb[i];
    float val = hh1[(size_t)i * 256 + t] * di * di + b1[t];
    #pragma unroll
    for (int e = 0; e < KNN; ++e) val += cf[e] * hh1[(size_t)src[e] * 256 + t];
    g[(size_t)i * 256 + t] = fmaxf(val, 0.f);
}

__global__ __launch_bounds__(256) void k_hh2(const float* __restrict__ g,
    const float* __restrict__ w2g, float* __restrict__ hh2)
{
    __shared__ float red[256];
    int i = blockIdx.x, t = threadIdx.x;
    float gg = g[(size_t)i * 256 + t];
    float s0 = blockReduceSum(gg * w2g[t * 2 + 0], red);
    float s1 = blockReduceSum(gg * w2g[t * 2 + 1], red);
    if (t == 0) { hh2[i * 2 + 0] = s0; hh2[i * 2 + 1] = s1; }
}

__global__ void k_gout(const float* __restrict__ hh2, const int* __restrict__ idxb,
    const float* __restrict__ wgt, const float* __restrict__ dinvb,
    const float* __restrict__ b2, float* __restrict__ out)
{
    int t = threadIdx.x;
    if (t < 16) {
        int i = t >> 1, c = t & 1;
        float di = dinvb[i];
        float val = hh2[i * 2 + c] * di * di + b2[c];
        for (int e = 0; e < KNN; ++e) {
            int s2 = idxb[i * KNN + e];
            val += wgt[i * KNN + e] * dinvb[s2] * di * hh2[s2 * 2 + c];
        }
        out[16 + i * 2 + c] = val;
    }
}

extern "C" void kernel_launch(void* const* d_in, const int* in_sizes, int n_in,
                              void* d_out, int out_size, void* d_ws, size_t ws_size,
                              hipStream_t stream)
{
    (void)in_sizes; (void)n_in; (void)out_size;
    const float* x     = (const float*)d_in[0];
    const float* fc1_w = (const float*)d_in[1];
    const float* fc1_b = (const float*)d_in[2];
    const float* cls   = (const float*)d_in[3];
    const float* lp[2][7];
    for (int l = 0; l < 2; ++l)
        for (int j = 0; j < 7; ++j)
            lp[l][j] = (const float*)d_in[4 + l * 7 + j];
    const float* w7 = (const float*)d_in[18]; const float* b7 = (const float*)d_in[19];
    const float* w5 = (const float*)d_in[20]; const float* b5 = (const float*)d_in[21];
    const float* w3 = (const float*)d_in[22]; const float* b3 = (const float*)d_in[23];
    const float* lnf_g = (const float*)d_in[24]; const float* lnf_b = (const float*)d_in[25];
    const float* fc2w = (const float*)d_in[26]; const float* fc2b = (const float*)d_in[27];
    const float* gw1 = (const float*)d_in[28]; const float* gb1 = (const float*)d_in[29];
    const float* gw2 = (const float*)d_in[30]; const float* gb2 = (const float*)d_in[31];
    const float* reh = (const float*)d_in[32];
    float* out = (float*)d_out;

    // Workspace budget: 92,943,144 floats = 371,772,576 bytes (ws has 376 MiB).
    const size_t REQUIRED = 92943144ull * 4ull;
    if (ws_size < REQUIRED) {
        k_diag<<<1, 32, 0, stream>>>(out, (float)ws_size);
        return;
    }

    float* Wf = (float*)d_ws;
    size_t off = 0;
    auto alloc = [&](size_t n) { float* p = Wf + off; off += n; return p; };
    float* h      = alloc((size_t)BB * NTOK * 512);
    float* lnstat = alloc((size_t)BB * NTOK * 2);
    u16* q16 = (u16*)alloc(12582912);   // BB*NPAD*512 u16 (full batch); ft overlay here
    u16* k16 = (u16*)alloc(6291456);    // CH*NPAD*512 u16 (chunk-local)
    u16* v16 = (u16*)alloc(12582912);   // full batch
    float* q_l  = alloc((size_t)CH * HEADS * 256 * 64);   // chunk-local
    float* k_l  = alloc((size_t)CH * HEADS * 256 * 64);   // chunk-local
    float* out3 = alloc((size_t)BB * HEADS * 256 * 64);   // both chunks
    u16* k_l16  = (u16*)alloc(524288);   // both chunks (1,048,576 u16)
    u16* w216   = (u16*)alloc(524288);   // both chunks
    float* bag  = alloc(8 * 512);
    float* xn   = alloc((size_t)MAXNN * 512);
    float* hh1  = alloc((size_t)MAXNN * 256);
    float* gbuf = alloc((size_t)MAXNN * 256);
    float* hh2  = alloc(MAXNN * 2);
    float* dinv = alloc(MAXNN);
    float* wgt  = alloc(MAXNN * KNN);
    int*   idxb = (int*)alloc(MAXNN * KNN);
    float* pvp   = alloc((size_t)32 * 256 * 8 * 64);
    float* pstat = alloc((size_t)32 * 256 * 16);
    float* attn2f = alloc(4194304);      // 64 batches x 65536 f32
    float* zF2    = alloc(4194304);      // 64 batches x 65536 f32
    u16* xp16  = (u16*)alloc(3145728);
    u16* at16  = (u16*)alloc(3145728);
    u16* a2b   = (u16*)alloc(2097152);   // 64 x 65536 u16
    u16* z16A  = (u16*)alloc(2097152);
    u16* z16B  = (u16*)alloc(2097152);
    u16* xz16  = (u16*)alloc(2097152);
    u16* p116  = (u16*)alloc(2097152);
    u16* p216  = (u16*)alloc(2097152);
    u16* fc1t  = (u16*)alloc(131072);
    u16* qkvt0 = (u16*)alloc(393216);
    u16* outt0 = (u16*)alloc(131072);
    u16* qkvt1 = (u16*)alloc(393216);
    u16* outt1 = (u16*)alloc(131072);

    // PPEG ft (24.92M f32) overlays q16+k16+v16 span (31.46M f32) — dead between layers
    float* ft = (float*)q16;
    const size_t QVOFF = (size_t)CH * HEADS * NPAD * 64;      // 12,582,912 u16 per chunk (q/v)
    const size_t LOFF  = (size_t)CH * HEADS * 256 * 64;       // 524,288 per chunk (k_l16/w216/out3)
    const size_t A2OFF = (size_t)32 * 65536;                  // per chunk (attn2/a2b)

    // preconvert/transpose all weights to bf16
    k_wconv<<<dim3(8, 8), 256, 0, stream>>>(fc1_w, 512, fc1t);
    k_wconv<<<dim3(24, 8), 256, 0, stream>>>(lp[0][2], 1536, qkvt0);
    k_wconv<<<dim3(8, 8), 256, 0, stream>>>(lp[0][3], 512, outt0);
    k_wconv<<<dim3(24, 8), 256, 0, stream>>>(lp[1][2], 1536, qkvt1);
    k_wconv<<<dim3(8, 8), 256, 0, stream>>>(lp[1][3], 512, outt1);

    // fc1 + relu -> h rows 1..6000, then wrap rows + cls
    k_gemm<1><<<dim3(4, 376), 256, 0, stream>>>(x, nullptr, fc1t, fc1_b, BB * NINST, 0,
                                                h, nullptr, nullptr, nullptr);
    k_fixup<<<dim3(BB, 85), 256, 0, stream>>>(h, cls);

    for (int l = 0; l < 2; ++l) {
        const float* ln_g  = lp[l][0];
        const float* ln_b  = lp[l][1];
        const u16* qkvt    = l == 0 ? qkvt0 : qkvt1;
        const u16* outt    = l == 0 ? outt0 : outt1;
        const float* out_b = lp[l][4];
        const float* res_w = lp[l][5];
        const float* res_b = lp[l][6];

        k_lnstat<<<BB * NTOK, 256, 0, stream>>>(h, lnstat);
        // phase A: per chunk qkv + attn3 + attn2
        for (int c = 0; c < NCHUNK; ++c) {
            int b0 = c * CH;
            k_lnbf<<<CH * NPAD, 256, 0, stream>>>(h, lnstat, ln_g, ln_b, b0, xp16);
            k_gemm<2><<<dim3(12, 192), 256, 0, stream>>>(nullptr, xp16, qkvt, nullptr, CH * NPAD, b0,
                                                         nullptr, q16 + c * QVOFF, k16, v16 + c * QVOFF);
            k_landmark<<<32 * 256, 64, 0, stream>>>(q16 + c * QVOFF, k16, q_l, k_l, k_l16 + c * LOFF);
            k_attn3_part<<<dim3(32, 4, 8), 256, 0, stream>>>(q_l, k16, v16 + c * QVOFF, pvp, pstat);
            k_attn3_comb<<<2048, 256, 0, stream>>>(pvp, pstat, out3 + c * LOFF);
            k_attn2<<<32 * 256, 256, 0, stream>>>(q_l, k_l, attn2f + c * A2OFF, a2b + c * A2OFF);
        }
        // batched pinv (64 batches = both chunks)
        k_pinv_init<<<64, 256, 0, stream>>>(attn2f, z16A);
        u16* zc16 = z16A; u16* zn16 = z16B;
        for (int it = 0; it < 6; ++it) {
            k_bgemm_b16<<<dim3(64, 4, 4), 256, 0, stream>>>(a2b, zc16, xz16, nullptr, 0.f, 1.f);
            k_bgemm_b16<<<dim3(64, 4, 4), 256, 0, stream>>>(xz16, xz16, p116, nullptr, 7.f, -1.f);
            k_bgemm_b16<<<dim3(64, 4, 4), 256, 0, stream>>>(xz16, p116, p216, nullptr, 15.f, -1.f);
            if (it < 5) {
                k_bgemm_b16<<<dim3(64, 4, 4), 256, 0, stream>>>(zc16, p216, zn16, nullptr, 3.25f, -0.25f);
                u16* tmp = zc16; zc16 = zn16; zn16 = tmp;
            } else {
                k_bgemm_b16<<<dim3(64, 4, 4), 256, 0, stream>>>(zc16, p216, nullptr, zF2, 3.25f, -0.25f);
            }
        }
        k_bgemm<<<dim3(64, 4, 1), 256, 0, stream>>>(zF2, out3, nullptr, w216, 64, 0.f, 1.f);
        // phase B: per chunk attn1 + proj
        for (int c = 0; c < NCHUNK; ++c) {
            int b0 = c * CH;
            k_attn1res<<<dim3(32, 96), 256, 0, stream>>>(q16 + c * QVOFF, k_l16 + c * LOFF,
                                                         w216 + c * LOFF, v16 + c * QVOFF,
                                                         res_w, res_b, at16);
            k_gemm<3><<<dim3(4, 192), 256, 0, stream>>>(nullptr, at16, outt, out_b, CH * NTOK, b0,
                                                        h, nullptr, nullptr, nullptr);
        }
        if (l == 0) {
            k_tr_fwd<<<dim3(96, 8, BB), 256, 0, stream>>>(h, ft);
            k_ppeg_t<<<BB * 512, 256, 0, stream>>>(ft, w7, b7, w5, b5, w3, b3);
            k_tr_bwd<<<dim3(96, 8, BB), 256, 0, stream>>>(ft, h);
        }
    }

    k_bag<<<BB, 256, 0, stream>>>(h, lnf_g, lnf_b, bag);
    k_mlp<<<1, 64, 0, stream>>>(bag, fc2w, fc2b, out);
    k_xcat<<<MAXNN, 256, 0, stream>>>(bag, reh, xn);
    k_sim_topk<<<MAXNN, 256, 0, stream>>>(xn, idxb, wgt, dinv);
    k_hh1<<<MAXNN, 256, 0, stream>>>(bag, gw1, hh1);
    k_g1<<<MAXNN, 256, 0, stream>>>(hh1, idxb, wgt, dinv, gb1, gbuf);
    k_hh2<<<MAXNN, 256, 0, stream>>>(gbuf, gw2, hh2);
    k_gout<<<1, 64, 0, stream>>>(hh2, idxb, wgt, dinv, gb2, out);
}